// Round 1
// baseline (1120.892 us; speedup 1.0000x reference)
//
#include <hip/hip_runtime.h>
#include <math.h>

#define Bc 4
#define Hc 8
#define Tc 8192
#define Dc 64
#define NCc 64
#define WSZc 128
#define BHc (Bc*Hc)
#define OUT_ELEMS (16777216u)   // B*H*T*D

// ---------------------------------------------------------------------------
// Kernel 1: dists[bh][c][t] = dot(l2norm(qk[bh][t]), means[h][c])  (fp64 accum)
// plus commitment-loss raw sum atomically added into loss_acc.
// ---------------------------------------------------------------------------
__global__ __launch_bounds__(256) void k_dists(const float* __restrict__ qk,
                                               const float* __restrict__ means,
                                               float* __restrict__ dists,
                                               float* __restrict__ loss_acc) {
    __shared__ float sm[NCc*Dc];       // means[h], 16 KB
    __shared__ float red[4];
    int tid = threadIdx.x;
    int blk = blockIdx.x;              // [0, BH*32)
    int bh  = blk >> 5;                // T/256 = 32 chunks per bh
    int chunk = blk & 31;
    int h = bh & (Hc-1);

    const float* mh = means + (size_t)h*NCc*Dc;
    for (int i = tid; i < NCc*Dc; i += 256) sm[i] = mh[i];
    __syncthreads();

    int t = chunk*256 + tid;
    const float* qrow = qk + ((size_t)bh*Tc + t)*Dc;
    float q[Dc];
    #pragma unroll
    for (int d = 0; d < Dc; d += 4) {
        float4 f = *(const float4*)(qrow + d);
        q[d] = f.x; q[d+1] = f.y; q[d+2] = f.z; q[d+3] = f.w;
    }
    double n2 = 0.0;
    #pragma unroll
    for (int d = 0; d < Dc; d++) n2 += (double)q[d]*(double)q[d];
    double nrm = sqrt(n2);
    if (nrm < 1e-12) nrm = 1e-12;
    double inv = 1.0/nrm;

    float best = -3.4e38f; int bc = 0;
    float* dbase = dists + ((size_t)bh*NCc)*Tc + (size_t)chunk*256 + tid;
    for (int c = 0; c < NCc; c++) {
        double acc = 0.0;
        const float* mc = sm + c*Dc;
        #pragma unroll
        for (int d = 0; d < Dc; d++) acc += (double)q[d]*(double)mc[d];
        float dv = (float)(acc*inv);
        dbase[(size_t)c*Tc] = dv;
        if (dv > best) { best = dv; bc = c; }   // strict > : first max wins (jnp.argmax)
    }
    // commitment loss term: sum_d (q/||q|| - m_best)^2
    double ls = 0.0;
    const float* mb = sm + bc*Dc;
    #pragma unroll
    for (int d = 0; d < Dc; d++) {
        double diff = (double)q[d]*inv - (double)mb[d];
        ls += diff*diff;
    }
    float lf = (float)ls;
    #pragma unroll
    for (int o = 32; o >= 1; o >>= 1) lf += __shfl_down(lf, o, 64);
    if ((tid & 63) == 0) red[tid >> 6] = lf;
    __syncthreads();
    if (tid == 0) atomicAdd(loss_acc, red[0]+red[1]+red[2]+red[3]);
}

// ---------------------------------------------------------------------------
// Kernel 2: per (bh,c) exact top-128 of 8192 by value (ties: lower index),
// then sort the 128 selected indices ascending.  Radix-select on ordered keys.
// ---------------------------------------------------------------------------
__global__ __launch_bounds__(256) void k_topk(const float* __restrict__ dists,
                                              int* __restrict__ indices) {
    __shared__ unsigned keys[Tc];      // 32 KB
    __shared__ unsigned hist[256];
    __shared__ unsigned sh_prefix;
    __shared__ int      sh_k;
    __shared__ int      cnt_gt, cnt_eq;
    __shared__ unsigned eqbuf[256];
    __shared__ unsigned sel[WSZc];

    int tid = threadIdx.x;
    int bhc = blockIdx.x;
    const float* dp = dists + (size_t)bhc*Tc;

    for (int t = tid; t < Tc; t += 256) {
        unsigned u = __float_as_uint(dp[t]);
        u = (u & 0x80000000u) ? ~u : (u | 0x80000000u);  // order-preserving map
        keys[t] = u;
    }
    if (tid == 0) { sh_k = WSZc; sh_prefix = 0u; cnt_gt = 0; cnt_eq = 0; }
    __syncthreads();

    for (int pass = 0; pass < 4; pass++) {
        int shift = 24 - 8*pass;
        for (int i = tid; i < 256; i += 256) hist[i] = 0u;
        __syncthreads();
        unsigned pref = sh_prefix;
        // 64-bit mask avoids UB for shift+8 == 32 (pass 0 -> mask low 32 bits = 0)
        unsigned long long hm = ~((1ull << (shift+8)) - 1ull);
        for (int t = tid; t < Tc; t += 256) {
            unsigned ky = keys[t];
            if ((((unsigned long long)ky) & hm) == (((unsigned long long)pref) & hm))
                atomicAdd(&hist[(ky >> shift) & 255u], 1u);
        }
        __syncthreads();
        if (tid == 0) {
            int k = sh_k; unsigned cum = 0; 
            for (int b = 255; b >= 0; b--) {
                unsigned hb = hist[b];
                if (cum + hb >= (unsigned)k) {
                    sh_k = k - (int)cum;
                    sh_prefix = pref | ((unsigned)b << shift);
                    break;
                }
                cum += hb;
            }
        }
        __syncthreads();
    }
    unsigned Kthr = sh_prefix;
    int kEq = sh_k;

    for (int t = tid; t < Tc; t += 256) {
        unsigned ky = keys[t];
        if (ky > Kthr) {
            int p = atomicAdd(&cnt_gt, 1);
            sel[p] = (unsigned)t;
        } else if (ky == Kthr) {
            int p = atomicAdd(&cnt_eq, 1);
            if (p < 256) eqbuf[p] = (unsigned)t;
        }
    }
    __syncthreads();
    int ce = cnt_eq; if (ce > 256) ce = 256;
    for (int i = tid; i < 256; i += 256) if (i >= ce) eqbuf[i] = 0xFFFFFFFFu;
    __syncthreads();
    // bitonic sort eqbuf[256] ascending (tie-break: keep smallest indices)
    for (int k2 = 2; k2 <= 256; k2 <<= 1) {
        for (int j = k2 >> 1; j >= 1; j >>= 1) {
            int i = tid, ixj = i ^ j;
            if (ixj > i) {
                bool up = ((i & k2) == 0);
                unsigned a = eqbuf[i], b = eqbuf[ixj];
                if ((a > b) == up) { eqbuf[i] = b; eqbuf[ixj] = a; }
            }
            __syncthreads();
        }
    }
    int cg = cnt_gt;
    if (tid < kEq) sel[cg + tid] = eqbuf[tid];
    __syncthreads();
    // bitonic sort sel[128] ascending
    for (int k2 = 2; k2 <= 128; k2 <<= 1) {
        for (int j = k2 >> 1; j >= 1; j >>= 1) {
            if (tid < 128) {
                int i = tid, ixj = i ^ j;
                if (ixj > i) {
                    bool up = ((i & k2) == 0);
                    unsigned a = sel[i], b = sel[ixj];
                    if ((a > b) == up) { sel[i] = b; sel[ixj] = a; }
                }
            }
            __syncthreads();
        }
    }
    if (tid < WSZc) indices[(size_t)bhc*WSZc + tid] = (int)sel[tid];
}

// ---------------------------------------------------------------------------
// Kernel 3: per (bh,c) fused attention over the 128 gathered tokens.
// scores kept transposed pt[j][i]; shift(rel)[i][j] = rel[i][127+j-i], j<=i.
// ---------------------------------------------------------------------------
__global__ __launch_bounds__(256) void k_attn(const float* __restrict__ qk,
                                              const float* __restrict__ v,
                                              const float* __restrict__ relw,
                                              const int* __restrict__ indices,
                                              float* __restrict__ out,
                                              float* __restrict__ denom) {
    __shared__ int   sidx[WSZc];
    __shared__ float sinv[WSZc];
    __shared__ float qt[Dc][WSZc];     // 32 KB, q transposed [d][i]
    __shared__ float wt[Dc][WSZc];     // 32 KB, rel_weights transposed [d][m]
    __shared__ float pt[WSZc][132];    // 66 KB, scores transposed [j][i] (+pad)

    int tid = threadIdx.x;
    int bhc = blockIdx.x;
    int bh  = bhc >> 6;                // NC = 64
    int h   = bh & (Hc-1);

    if (tid < WSZc) sidx[tid] = indices[(size_t)bhc*WSZc + tid];
    __syncthreads();

    {   // stage q rows (gathered) and rel_weights rows, transposed into LDS
        int i = tid >> 1, half = tid & 1;
        const float* qrow = qk   + ((size_t)bh*Tc + sidx[i])*Dc + half*32;
        const float* wrow = relw + ((size_t)i*Hc + h)*Dc + half*32;
        #pragma unroll
        for (int k = 0; k < 32; k += 4) {
            float4 fq = *(const float4*)(qrow + k);
            float4 fw = *(const float4*)(wrow + k);
            int d = half*32 + k;
            qt[d+0][i] = fq.x; qt[d+1][i] = fq.y; qt[d+2][i] = fq.z; qt[d+3][i] = fq.w;
            wt[d+0][i] = fw.x; wt[d+1][i] = fw.y; wt[d+2][i] = fw.z; wt[d+3][i] = fw.w;
        }
    }
    for (int i = tid; i < WSZc*132; i += 256) (&pt[0][0])[i] = 0.0f;
    __syncthreads();

    if (tid < WSZc) {   // sinv[j] = scale / max(||q_j||, 1e-12)
        float n2 = 0.0f;
        #pragma unroll
        for (int d = 0; d < Dc; d++) { float x = qt[d][tid]; n2 += x*x; }
        float nr = sqrtf(n2);
        if (nr < 1e-12f) nr = 1e-12f;
        sinv[tid] = 0.125f / nr;
    }
    __syncthreads();

    int ty = tid >> 4, tx = tid & 15;
    int i0 = ty*8, j0 = tx*8;

    {   // A1: rel[i][m] = q_i . rw_m ; scatter scaled into pt[m-127+i][i]
        float acc[8][8];
        #pragma unroll
        for (int a = 0; a < 8; a++)
            #pragma unroll
            for (int b = 0; b < 8; b++) acc[a][b] = 0.0f;
        for (int d = 0; d < Dc; d++) {
            float4 qa = *(const float4*)&qt[d][i0];
            float4 qb = *(const float4*)&qt[d][i0+4];
            float4 wa = *(const float4*)&wt[d][j0];
            float4 wb = *(const float4*)&wt[d][j0+4];
            float qv[8] = {qa.x,qa.y,qa.z,qa.w,qb.x,qb.y,qb.z,qb.w};
            float wv[8] = {wa.x,wa.y,wa.z,wa.w,wb.x,wb.y,wb.z,wb.w};
            #pragma unroll
            for (int a = 0; a < 8; a++)
                #pragma unroll
                for (int b = 0; b < 8; b++) acc[a][b] += qv[a]*wv[b];
        }
        #pragma unroll
        for (int a = 0; a < 8; a++) {
            #pragma unroll
            for (int b = 0; b < 8; b++) {
                int i = i0 + a, m = j0 + b;
                int j = m - (WSZc-1) + i;
                if (j >= 0) pt[j][i] = acc[a][b]*0.125f;
            }
        }
    }
    __syncthreads();

    {   // A2: G = q.qT ; combine with rel, diag mask, store back
        float acc[8][8];
        #pragma unroll
        for (int a = 0; a < 8; a++)
            #pragma unroll
            for (int b = 0; b < 8; b++) acc[a][b] = 0.0f;
        for (int d = 0; d < Dc; d++) {
            float4 qa = *(const float4*)&qt[d][i0];
            float4 qb = *(const float4*)&qt[d][i0+4];
            float4 ka = *(const float4*)&qt[d][j0];
            float4 kb = *(const float4*)&qt[d][j0+4];
            float qv[8] = {qa.x,qa.y,qa.z,qa.w,qb.x,qb.y,qb.z,qb.w};
            float kv[8] = {ka.x,ka.y,ka.z,ka.w,kb.x,kb.y,kb.z,kb.w};
            #pragma unroll
            for (int a = 0; a < 8; a++)
                #pragma unroll
                for (int b = 0; b < 8; b++) acc[a][b] += qv[a]*kv[b];
        }
        #pragma unroll
        for (int a = 0; a < 8; a++) {
            #pragma unroll
            for (int b = 0; b < 8; b++) {
                int i = i0 + a, j = j0 + b;
                float s = (i == j) ? -50000.0f : (acc[a][b]*sinv[j] + pt[j][i]);
                pt[j][i] = s;
            }
        }
    }
    __syncthreads();

    float* vbuf = &qt[0][0];   // reuse q LDS (dead) for v rows, row-major [j][d]
    if (tid < WSZc) {
        // softmax over row i (stored as column i of pt) — conflict-free lanes
        int i = tid;
        float mx = -3.4e38f;
        for (int j = 0; j < WSZc; j++) mx = fmaxf(mx, pt[j][i]);
        float sum = 0.0f;
        for (int j = 0; j < WSZc; j++) { float e = expf(pt[j][i]-mx); pt[j][i] = e; sum += e; }
        float r = 1.0f/sum;
        for (int j = 0; j < WSZc; j++) pt[j][i] *= r;
    } else {
        int j = tid - WSZc;
        const float* vrow = v + ((size_t)bh*Tc + sidx[j])*Dc;
        #pragma unroll
        for (int k = 0; k < Dc; k += 4)
            *(float4*)(vbuf + j*Dc + k) = *(const float4*)(vrow + k);
    }
    __syncthreads();

    {   // C: bo[i][d] = sum_j P[i][j] * v[j][d] ; scatter-add to out/denom
        int tyc = tid >> 3, txc = tid & 7;
        int ii0 = tyc*4, d0 = txc*8;
        float acc[4][8];
        #pragma unroll
        for (int a = 0; a < 4; a++)
            #pragma unroll
            for (int b = 0; b < 8; b++) acc[a][b] = 0.0f;
        for (int j = 0; j < WSZc; j++) {
            float4 p4 = *(const float4*)&pt[j][ii0];
            float pv[4] = {p4.x, p4.y, p4.z, p4.w};
            float4 va = *(const float4*)(vbuf + j*Dc + d0);
            float4 vb = *(const float4*)(vbuf + j*Dc + d0 + 4);
            float vv[8] = {va.x,va.y,va.z,va.w,vb.x,vb.y,vb.z,vb.w};
            #pragma unroll
            for (int a = 0; a < 4; a++)
                #pragma unroll
                for (int b = 0; b < 8; b++) acc[a][b] += pv[a]*vv[b];
        }
        #pragma unroll
        for (int a = 0; a < 4; a++) {
            int tok = sidx[ii0 + a];
            float* op = out + ((size_t)bh*Tc + tok)*Dc + d0;
            #pragma unroll
            for (int b = 0; b < 8; b++) atomicAdd(op + b, acc[a][b]);
            if (txc == 0) atomicAdd(denom + (size_t)bh*Tc + tok, 1.0f);
        }
    }
}

// ---------------------------------------------------------------------------
// Kernel 4: out = numer / (denom + EPS); scale the raw loss sum.
// ---------------------------------------------------------------------------
__global__ __launch_bounds__(256) void k_finalize(float* __restrict__ out,
                                                  const float* __restrict__ denom) {
    size_t g = (size_t)blockIdx.x*256 + threadIdx.x;   // one float4 per thread
    float4* o4 = (float4*)out;
    float4 vv = o4[g];
    float dn = denom[g >> 4];                           // (g*4)/64
    float r = 1.0f / (dn + 1e-5f);
    vv.x *= r; vv.y *= r; vv.z *= r; vv.w *= r;
    o4[g] = vv;
    if (blockIdx.x == 0 && threadIdx.x == 0) {
        // COMMITMENT / (B*H*T*D) = 1e-4 / 16777216
        out[OUT_ELEMS] = out[OUT_ELEMS] * (float)(1e-4 / 16777216.0);
    }
}

extern "C" void kernel_launch(void* const* d_in, const int* in_sizes, int n_in,
                              void* d_out, int out_size, void* d_ws, size_t ws_size,
                              hipStream_t stream) {
    const float* qk    = (const float*)d_in[0];
    const float* v     = (const float*)d_in[1];
    const float* means = (const float*)d_in[2];
    const float* relw  = (const float*)d_in[3];
    float* out = (float*)d_out;
    char*  ws  = (char*)d_ws;

    // workspace layout
    float* dists   = (float*)ws;                                         // 64 MB
    int*   indices = (int*)(ws + (size_t)BHc*NCc*Tc*4);                  // 1 MB
    float* denom   = (float*)(ws + (size_t)BHc*NCc*Tc*4
                                 + (size_t)BHc*NCc*WSZc*4);              // 1 MB

    hipMemsetAsync(d_out, 0, (size_t)out_size*sizeof(float), stream);
    hipMemsetAsync(denom, 0, (size_t)BHc*Tc*sizeof(float), stream);

    k_dists   <<<BHc*(Tc/256), 256, 0, stream>>>(qk, means, dists, out + OUT_ELEMS);
    k_topk    <<<BHc*NCc,      256, 0, stream>>>(dists, indices);
    k_attn    <<<BHc*NCc,      256, 0, stream>>>(qk, v, relw, indices, out, denom);
    k_finalize<<<OUT_ELEMS/4/256, 256, 0, stream>>>(out, denom);
}

// Round 2
// 918.492 us; speedup vs baseline: 1.2204x; 1.2204x over previous
//
#include <hip/hip_runtime.h>
#include <math.h>

typedef _Float16 h16;
typedef _Float16 half4 __attribute__((ext_vector_type(4)));
typedef _Float16 half8 __attribute__((ext_vector_type(8)));

#define Bc 4
#define Hc 8
#define Tc 8192
#define Dc 64
#define NCc 64
#define WSZc 128
#define BHc (Bc*Hc)
#define OUT_ELEMS (16777216u)   // B*H*T*D

// ---------------------------------------------------------------------------
// Kernel 1: dists[bh][c][t] = dot(l2norm(qk[bh][t]), means[h][c])  (fp32)
// plus commitment-loss raw sum atomically added into loss_acc.
// ---------------------------------------------------------------------------
__global__ __launch_bounds__(256) void k_dists(const float* __restrict__ qk,
                                               const float* __restrict__ means,
                                               float* __restrict__ dists,
                                               float* __restrict__ loss_acc) {
    __shared__ float sm[NCc*Dc];       // means[h], 16 KB
    __shared__ float red[4];
    int tid = threadIdx.x;
    int blk = blockIdx.x;              // [0, BH*32)
    int bh  = blk >> 5;                // T/256 = 32 chunks per bh
    int chunk = blk & 31;
    int h = bh & (Hc-1);

    const float* mh = means + (size_t)h*NCc*Dc;
    for (int i = tid; i < NCc*Dc; i += 256) sm[i] = mh[i];
    __syncthreads();

    int t = chunk*256 + tid;
    const float* qrow = qk + ((size_t)bh*Tc + t)*Dc;
    float q[Dc];
    #pragma unroll
    for (int d = 0; d < Dc; d += 4) {
        float4 f = *(const float4*)(qrow + d);
        q[d] = f.x; q[d+1] = f.y; q[d+2] = f.z; q[d+3] = f.w;
    }
    float n2 = 0.f;
    #pragma unroll
    for (int d = 0; d < Dc; d++) n2 += q[d]*q[d];
    float nrm = sqrtf(n2);
    if (nrm < 1e-12f) nrm = 1e-12f;
    float inv = 1.0f/nrm;

    float best = -3.4e38f; int bc = 0;
    float* dbase = dists + ((size_t)bh*NCc)*Tc + (size_t)chunk*256 + tid;
    for (int c = 0; c < NCc; c++) {
        float acc = 0.f;
        const float* mc = sm + c*Dc;
        #pragma unroll
        for (int d = 0; d < Dc; d++) acc += q[d]*mc[d];
        float dv = acc*inv;
        dbase[(size_t)c*Tc] = dv;
        if (dv > best) { best = dv; bc = c; }   // strict > : first max wins (jnp.argmax)
    }
    // commitment loss term: sum_d (q/||q|| - m_best)^2
    float ls = 0.f;
    const float* mb = sm + bc*Dc;
    #pragma unroll
    for (int d = 0; d < Dc; d++) {
        float diff = q[d]*inv - mb[d];
        ls += diff*diff;
    }
    float lf = ls;
    #pragma unroll
    for (int o = 32; o >= 1; o >>= 1) lf += __shfl_down(lf, o, 64);
    if ((tid & 63) == 0) red[tid >> 6] = lf;
    __syncthreads();
    if (tid == 0) atomicAdd(loss_acc, red[0]+red[1]+red[2]+red[3]);
}

// ---------------------------------------------------------------------------
// Kernel 2: per (bh,c) exact top-128 of 8192 by value (ties: lower index),
// then sort the 128 selected indices ascending.  Radix-select on ordered keys.
// ---------------------------------------------------------------------------
__global__ __launch_bounds__(256) void k_topk(const float* __restrict__ dists,
                                              int* __restrict__ indices) {
    __shared__ unsigned keys[Tc];      // 32 KB
    __shared__ unsigned hist[256];
    __shared__ unsigned sh_prefix;
    __shared__ int      sh_k;
    __shared__ int      cnt_gt, cnt_eq;
    __shared__ unsigned eqbuf[256];
    __shared__ unsigned sel[WSZc];

    int tid = threadIdx.x;
    int bhc = blockIdx.x;
    const float* dp = dists + (size_t)bhc*Tc;

    for (int t = tid; t < Tc; t += 256) {
        unsigned u = __float_as_uint(dp[t]);
        u = (u & 0x80000000u) ? ~u : (u | 0x80000000u);  // order-preserving map
        keys[t] = u;
    }
    if (tid == 0) { sh_k = WSZc; sh_prefix = 0u; cnt_gt = 0; cnt_eq = 0; }
    __syncthreads();

    for (int pass = 0; pass < 4; pass++) {
        int shift = 24 - 8*pass;
        for (int i = tid; i < 256; i += 256) hist[i] = 0u;
        __syncthreads();
        unsigned pref = sh_prefix;
        unsigned long long hm = ~((1ull << (shift+8)) - 1ull);
        for (int t = tid; t < Tc; t += 256) {
            unsigned ky = keys[t];
            if ((((unsigned long long)ky) & hm) == (((unsigned long long)pref) & hm))
                atomicAdd(&hist[(ky >> shift) & 255u], 1u);
        }
        __syncthreads();
        if (tid == 0) {
            int k = sh_k; unsigned cum = 0;
            for (int b = 255; b >= 0; b--) {
                unsigned hb = hist[b];
                if (cum + hb >= (unsigned)k) {
                    sh_k = k - (int)cum;
                    sh_prefix = pref | ((unsigned)b << shift);
                    break;
                }
                cum += hb;
            }
        }
        __syncthreads();
    }
    unsigned Kthr = sh_prefix;
    int kEq = sh_k;

    for (int t = tid; t < Tc; t += 256) {
        unsigned ky = keys[t];
        if (ky > Kthr) {
            int p = atomicAdd(&cnt_gt, 1);
            sel[p] = (unsigned)t;
        } else if (ky == Kthr) {
            int p = atomicAdd(&cnt_eq, 1);
            if (p < 256) eqbuf[p] = (unsigned)t;
        }
    }
    __syncthreads();
    int ce = cnt_eq; if (ce > 256) ce = 256;
    for (int i = tid; i < 256; i += 256) if (i >= ce) eqbuf[i] = 0xFFFFFFFFu;
    __syncthreads();
    for (int k2 = 2; k2 <= 256; k2 <<= 1) {
        for (int j = k2 >> 1; j >= 1; j >>= 1) {
            int i = tid, ixj = i ^ j;
            if (ixj > i) {
                bool up = ((i & k2) == 0);
                unsigned a = eqbuf[i], b = eqbuf[ixj];
                if ((a > b) == up) { eqbuf[i] = b; eqbuf[ixj] = a; }
            }
            __syncthreads();
        }
    }
    int cg = cnt_gt;
    if (tid < kEq) sel[cg + tid] = eqbuf[tid];
    __syncthreads();
    for (int k2 = 2; k2 <= 128; k2 <<= 1) {
        for (int j = k2 >> 1; j >= 1; j >>= 1) {
            if (tid < 128) {
                int i = tid, ixj = i ^ j;
                if (ixj > i) {
                    bool up = ((i & k2) == 0);
                    unsigned a = sel[i], b = sel[ixj];
                    if ((a > b) == up) { sel[i] = b; sel[ixj] = a; }
                }
            }
            __syncthreads();
        }
    }
    if (tid < WSZc) indices[(size_t)bhc*WSZc + tid] = (int)sel[tid];
}

// ---------------------------------------------------------------------------
// Kernel 3: per (bh,c) fused attention, fp16 LDS staging, in-register softmax.
// Block swizzle: blk = g*512 + c*8 + x so XCD x (== blockIdx%8) owns bh=g*8+x
// at a time -> out-atomics stay in that XCD's L2.
// shift(rel)[i][j] = rel[i][127+j-i] for j<=i else 0.
// ---------------------------------------------------------------------------
__global__ __launch_bounds__(256, 2) void k_attn(const float* __restrict__ qk,
                                                 const float* __restrict__ v,
                                                 const float* __restrict__ relw,
                                                 const int* __restrict__ indices,
                                                 float* __restrict__ out,
                                                 float* __restrict__ denom) {
    __shared__ __align__(16) h16 qh[Dc][136];     // q^T [d][i], 17408 B
    __shared__ __align__(16) h16 wv[9216];        // rel_w^T [d][m] s136 / later v [j][d] s72
    __shared__ __align__(16) h16 pt[WSZc][132];   // rel then P, transposed [j][i], 33792 B
    __shared__ int   sidx[WSZc];
    __shared__ float sinv[WSZc];

    int tid = threadIdx.x;
    int blk = blockIdx.x;
    int x = blk & 7, g = blk >> 9, c = (blk >> 3) & 63;
    int bh = g*8 + x;
    int h  = bh & (Hc-1);
    int bhc = bh*NCc + c;

    for (int i2 = tid; i2 < (WSZc*132)/2; i2 += 256) ((unsigned*)pt)[i2] = 0u;
    if (tid < WSZc) sidx[tid] = indices[(size_t)bhc*WSZc + tid];
    __syncthreads();

    {   // stage q rows (gathered) and rel_weights rows, fp32->fp16, transposed
        int i = tid >> 1, hf = tid & 1;
        const float* qrow = qk   + ((size_t)bh*Tc + sidx[i])*Dc + hf*32;
        const float* wrow = relw + ((size_t)i*Hc + h)*Dc + hf*32;
        #pragma unroll
        for (int k = 0; k < 32; k += 4) {
            float4 fq = *(const float4*)(qrow + k);
            float4 fw = *(const float4*)(wrow + k);
            int d = hf*32 + k;
            qh[d+0][i] = (h16)fq.x; qh[d+1][i] = (h16)fq.y;
            qh[d+2][i] = (h16)fq.z; qh[d+3][i] = (h16)fq.w;
            wv[(d+0)*136 + i] = (h16)fw.x; wv[(d+1)*136 + i] = (h16)fw.y;
            wv[(d+2)*136 + i] = (h16)fw.z; wv[(d+3)*136 + i] = (h16)fw.w;
        }
    }
    __syncthreads();

    if (tid < WSZc) {   // sinv[j] = scale / max(||k_j||, 1e-12)
        float n2 = 0.f;
        #pragma unroll 8
        for (int d = 0; d < Dc; d++) { float xq = (float)qh[d][tid]; n2 += xq*xq; }
        float nr = sqrtf(n2);
        if (nr < 1e-12f) nr = 1e-12f;
        sinv[tid] = 0.125f / nr;
    }
    __syncthreads();

    int ty = tid >> 4, tx = tid & 15;
    int i0 = ty*8, j0 = tx*8;

    {   // A1: rel[i][m] = q_i . rw_m ; scatter scaled into pt[m-127+i][i]
        float acc[8][8];
        #pragma unroll
        for (int a = 0; a < 8; a++)
            #pragma unroll
            for (int b = 0; b < 8; b++) acc[a][b] = 0.0f;
        #pragma unroll 4
        for (int d = 0; d < Dc; d++) {
            half8 hq = *(const half8*)&qh[d][i0];
            half8 hw = *(const half8*)&wv[d*136 + j0];
            float qv[8], wvv[8];
            #pragma unroll
            for (int k2 = 0; k2 < 8; k2++) { qv[k2] = (float)hq[k2]; wvv[k2] = (float)hw[k2]; }
            #pragma unroll
            for (int a = 0; a < 8; a++)
                #pragma unroll
                for (int b = 0; b < 8; b++) acc[a][b] += qv[a]*wvv[b];
        }
        #pragma unroll
        for (int a = 0; a < 8; a++) {
            #pragma unroll
            for (int b = 0; b < 8; b++) {
                int i = i0 + a, m = j0 + b;
                int j = m - (WSZc-1) + i;
                if (j >= 0) pt[j][i] = (h16)(acc[a][b]*0.125f);
            }
        }
    }
    __syncthreads();

    // prefetch v rows (gathered) into registers; overlaps A2 compute
    float4 vreg[8];
    {
        int vj = tid >> 1, vh = tid & 1;
        const float* vrow = v + ((size_t)bh*Tc + sidx[vj])*Dc + vh*32;
        #pragma unroll
        for (int r = 0; r < 8; r++) vreg[r] = *(const float4*)(vrow + r*4);
    }

    float acc[8][8];
    {   // A2: S = (q.q^T)*sinv + rel, diag mask  (S stays in registers)
        #pragma unroll
        for (int a = 0; a < 8; a++)
            #pragma unroll
            for (int b = 0; b < 8; b++) acc[a][b] = 0.0f;
        #pragma unroll 4
        for (int d = 0; d < Dc; d++) {
            half8 hq = *(const half8*)&qh[d][i0];
            half8 hk = *(const half8*)&qh[d][j0];
            float qv[8], kv[8];
            #pragma unroll
            for (int k2 = 0; k2 < 8; k2++) { qv[k2] = (float)hq[k2]; kv[k2] = (float)hk[k2]; }
            #pragma unroll
            for (int a = 0; a < 8; a++)
                #pragma unroll
                for (int b = 0; b < 8; b++) acc[a][b] += qv[a]*kv[b];
        }
        #pragma unroll
        for (int b = 0; b < 8; b++) {
            int j = j0 + b;
            float sj = sinv[j];
            #pragma unroll
            for (int a = 0; a < 8; a++) {
                int i = i0 + a;
                float rel = (float)pt[j][i];
                float s = acc[a][b]*sj + rel;
                if (i == j) s = -50000.0f;
                acc[a][b] = s;
            }
        }
    }
    __syncthreads();   // all rel reads from pt done; pt reusable for P

    {   // store v regs -> LDS (wv space, rel_w is dead), fp16 rows [j][d] s72
        int vj = tid >> 1, vh = tid & 1;
        h16* vb = &wv[vj*72 + vh*32];
        #pragma unroll
        for (int r = 0; r < 4; r++) {
            half8 hv;
            float4 f0 = vreg[2*r], f1 = vreg[2*r+1];
            hv[0]=(h16)f0.x; hv[1]=(h16)f0.y; hv[2]=(h16)f0.z; hv[3]=(h16)f0.w;
            hv[4]=(h16)f1.x; hv[5]=(h16)f1.y; hv[6]=(h16)f1.z; hv[7]=(h16)f1.w;
            *(half8*)(vb + r*8) = hv;
        }
    }

    {   // in-register softmax across the 16-lane tx-group (rows i0..i0+7)
        float rmax[8], rsum[8];
        #pragma unroll
        for (int a = 0; a < 8; a++) {
            float m = acc[a][0];
            #pragma unroll
            for (int b = 1; b < 8; b++) m = fmaxf(m, acc[a][b]);
            #pragma unroll
            for (int st = 1; st <= 8; st <<= 1) m = fmaxf(m, __shfl_xor(m, st, 64));
            rmax[a] = m;
        }
        #pragma unroll
        for (int a = 0; a < 8; a++) {
            float s = 0.f;
            #pragma unroll
            for (int b = 0; b < 8; b++) {
                float e = __expf(acc[a][b] - rmax[a]);
                acc[a][b] = e; s += e;
            }
            #pragma unroll
            for (int st = 1; st <= 8; st <<= 1) s += __shfl_xor(s, st, 64);
            rsum[a] = 1.0f / s;
        }
        // write P (post-softmax, fp16) transposed: pt[j][i]
        #pragma unroll
        for (int b = 0; b < 8; b++) {
            half4 p0, p1;
            #pragma unroll
            for (int a = 0; a < 4; a++) p0[a] = (h16)(acc[a][b]*rsum[a]);
            #pragma unroll
            for (int a = 0; a < 4; a++) p1[a] = (h16)(acc[a+4][b]*rsum[a+4]);
            *(half4*)&pt[j0+b][i0]   = p0;
            *(half4*)&pt[j0+b][i0+4] = p1;
        }
    }
    __syncthreads();

    {   // C: bo[i][d] = sum_j P[i][j]*v[j][d] ; scatter-add to out/denom
        int tyc = tid >> 3, txc = tid & 7;
        int ii0 = tyc*4, d0 = txc*8;
        float acc2[4][8];
        #pragma unroll
        for (int a = 0; a < 4; a++)
            #pragma unroll
            for (int b = 0; b < 8; b++) acc2[a][b] = 0.0f;
        #pragma unroll 2
        for (int j = 0; j < WSZc; j++) {
            half4 hp = *(const half4*)&pt[j][ii0];
            half8 hv = *(const half8*)&wv[j*72 + d0];
            float pv[4], vvv[8];
            #pragma unroll
            for (int k2 = 0; k2 < 4; k2++) pv[k2] = (float)hp[k2];
            #pragma unroll
            for (int k2 = 0; k2 < 8; k2++) vvv[k2] = (float)hv[k2];
            #pragma unroll
            for (int a = 0; a < 4; a++)
                #pragma unroll
                for (int b = 0; b < 8; b++) acc2[a][b] += pv[a]*vvv[b];
        }
        #pragma unroll
        for (int a = 0; a < 4; a++) {
            int tok = sidx[ii0 + a];
            float* op = out + ((size_t)bh*Tc + tok)*Dc + d0;
            #pragma unroll
            for (int b = 0; b < 8; b++) atomicAdd(op + b, acc2[a][b]);
            if (txc == 0) atomicAdd(denom + (size_t)bh*Tc + tok, 1.0f);
        }
    }
}

// ---------------------------------------------------------------------------
// Kernel 4: out = numer / (denom + EPS); scale the raw loss sum.
// ---------------------------------------------------------------------------
__global__ __launch_bounds__(256) void k_finalize(float* __restrict__ out,
                                                  const float* __restrict__ denom) {
    size_t g = (size_t)blockIdx.x*256 + threadIdx.x;   // one float4 per thread
    float4* o4 = (float4*)out;
    float4 vv = o4[g];
    float dn = denom[g >> 4];
    float r = 1.0f / (dn + 1e-5f);
    vv.x *= r; vv.y *= r; vv.z *= r; vv.w *= r;
    o4[g] = vv;
    if (blockIdx.x == 0 && threadIdx.x == 0) {
        out[OUT_ELEMS] = out[OUT_ELEMS] * (float)(1e-4 / 16777216.0);
    }
}

extern "C" void kernel_launch(void* const* d_in, const int* in_sizes, int n_in,
                              void* d_out, int out_size, void* d_ws, size_t ws_size,
                              hipStream_t stream) {
    const float* qk    = (const float*)d_in[0];
    const float* v     = (const float*)d_in[1];
    const float* means = (const float*)d_in[2];
    const float* relw  = (const float*)d_in[3];
    float* out = (float*)d_out;
    char*  ws  = (char*)d_ws;

    float* dists   = (float*)ws;                                         // 64 MB
    int*   indices = (int*)(ws + (size_t)BHc*NCc*Tc*4);                  // 1 MB
    float* denom   = (float*)(ws + (size_t)BHc*NCc*Tc*4
                                 + (size_t)BHc*NCc*WSZc*4);              // 1 MB

    hipMemsetAsync(d_out, 0, (size_t)out_size*sizeof(float), stream);
    hipMemsetAsync(denom, 0, (size_t)BHc*Tc*sizeof(float), stream);

    k_dists   <<<BHc*(Tc/256), 256, 0, stream>>>(qk, means, dists, out + OUT_ELEMS);
    k_topk    <<<BHc*NCc,      256, 0, stream>>>(dists, indices);
    k_attn    <<<BHc*NCc,      256, 0, stream>>>(qk, v, relw, indices, out, denom);
    k_finalize<<<OUT_ELEMS/4/256, 256, 0, stream>>>(out, denom);
}

// Round 3
// 632.784 us; speedup vs baseline: 1.7714x; 1.4515x over previous
//
#include <hip/hip_runtime.h>
#include <math.h>

typedef _Float16 h16;
typedef _Float16 half4 __attribute__((ext_vector_type(4)));
typedef _Float16 half8 __attribute__((ext_vector_type(8)));

#define Bc 4
#define Hc 8
#define Tc 8192
#define Dc 64
#define NCc 64
#define WSZc 128
#define BHc (Bc*Hc)
#define MAXPc 16
#define OVFCAP 4095
#define OUT_ELEMS (16777216u)   // B*H*T*D

// ---------------------------------------------------------------------------
// Kernel 1: dists[bh][c][t] = dot(l2norm(qk[bh][t]), means[h][c])  (fp32)
// plus commitment-loss raw sum atomically added into loss_acc.
// ---------------------------------------------------------------------------
__global__ __launch_bounds__(256) void k_dists(const float* __restrict__ qk,
                                               const float* __restrict__ means,
                                               float* __restrict__ dists,
                                               float* __restrict__ loss_acc) {
    __shared__ float sm[NCc*Dc];       // means[h], 16 KB
    __shared__ float red[4];
    int tid = threadIdx.x;
    int blk = blockIdx.x;              // [0, BH*32)
    int bh  = blk >> 5;                // T/256 = 32 chunks per bh
    int chunk = blk & 31;
    int h = bh & (Hc-1);

    const float* mh = means + (size_t)h*NCc*Dc;
    for (int i = tid; i < NCc*Dc; i += 256) sm[i] = mh[i];
    __syncthreads();

    int t = chunk*256 + tid;
    const float* qrow = qk + ((size_t)bh*Tc + t)*Dc;
    float q[Dc];
    #pragma unroll
    for (int d = 0; d < Dc; d += 4) {
        float4 f = *(const float4*)(qrow + d);
        q[d] = f.x; q[d+1] = f.y; q[d+2] = f.z; q[d+3] = f.w;
    }
    float n2 = 0.f;
    #pragma unroll
    for (int d = 0; d < Dc; d++) n2 += q[d]*q[d];
    float nrm = sqrtf(n2);
    if (nrm < 1e-12f) nrm = 1e-12f;
    float inv = 1.0f/nrm;

    float best = -3.4e38f; int bc = 0;
    float* dbase = dists + ((size_t)bh*NCc)*Tc + (size_t)chunk*256 + tid;
    for (int c = 0; c < NCc; c++) {
        float acc = 0.f;
        const float* mc = sm + c*Dc;
        #pragma unroll
        for (int d = 0; d < Dc; d++) acc += q[d]*mc[d];
        float dv = acc*inv;
        dbase[(size_t)c*Tc] = dv;
        if (dv > best) { best = dv; bc = c; }   // strict > : first max wins (jnp.argmax)
    }
    float ls = 0.f;
    const float* mb = sm + bc*Dc;
    #pragma unroll
    for (int d = 0; d < Dc; d++) {
        float diff = q[d]*inv - mb[d];
        ls += diff*diff;
    }
    float lf = ls;
    #pragma unroll
    for (int o = 32; o >= 1; o >>= 1) lf += __shfl_down(lf, o, 64);
    if ((tid & 63) == 0) red[tid >> 6] = lf;
    __syncthreads();
    if (tid == 0) atomicAdd(loss_acc, red[0]+red[1]+red[2]+red[3]);
}

// ---------------------------------------------------------------------------
// Kernel 2: per (bh,c) exact top-128 of 8192 (ties: lower index), sorted asc.
// ---------------------------------------------------------------------------
__global__ __launch_bounds__(256) void k_topk(const float* __restrict__ dists,
                                              int* __restrict__ indices) {
    __shared__ unsigned keys[Tc];      // 32 KB
    __shared__ unsigned hist[256];
    __shared__ unsigned sh_prefix;
    __shared__ int      sh_k;
    __shared__ int      cnt_gt, cnt_eq;
    __shared__ unsigned eqbuf[256];
    __shared__ unsigned sel[WSZc];

    int tid = threadIdx.x;
    int bhc = blockIdx.x;
    const float* dp = dists + (size_t)bhc*Tc;

    for (int t = tid; t < Tc; t += 256) {
        unsigned u = __float_as_uint(dp[t]);
        u = (u & 0x80000000u) ? ~u : (u | 0x80000000u);  // order-preserving map
        keys[t] = u;
    }
    if (tid == 0) { sh_k = WSZc; sh_prefix = 0u; cnt_gt = 0; cnt_eq = 0; }
    __syncthreads();

    for (int pass = 0; pass < 4; pass++) {
        int shift = 24 - 8*pass;
        for (int i = tid; i < 256; i += 256) hist[i] = 0u;
        __syncthreads();
        unsigned pref = sh_prefix;
        unsigned long long hm = ~((1ull << (shift+8)) - 1ull);
        for (int t = tid; t < Tc; t += 256) {
            unsigned ky = keys[t];
            if ((((unsigned long long)ky) & hm) == (((unsigned long long)pref) & hm))
                atomicAdd(&hist[(ky >> shift) & 255u], 1u);
        }
        __syncthreads();
        if (tid == 0) {
            int k = sh_k; unsigned cum = 0;
            for (int b = 255; b >= 0; b--) {
                unsigned hb = hist[b];
                if (cum + hb >= (unsigned)k) {
                    sh_k = k - (int)cum;
                    sh_prefix = pref | ((unsigned)b << shift);
                    break;
                }
                cum += hb;
            }
        }
        __syncthreads();
    }
    unsigned Kthr = sh_prefix;
    int kEq = sh_k;

    for (int t = tid; t < Tc; t += 256) {
        unsigned ky = keys[t];
        if (ky > Kthr) {
            int p = atomicAdd(&cnt_gt, 1);
            sel[p] = (unsigned)t;
        } else if (ky == Kthr) {
            int p = atomicAdd(&cnt_eq, 1);
            if (p < 256) eqbuf[p] = (unsigned)t;
        }
    }
    __syncthreads();
    int ce = cnt_eq; if (ce > 256) ce = 256;
    for (int i = tid; i < 256; i += 256) if (i >= ce) eqbuf[i] = 0xFFFFFFFFu;
    __syncthreads();
    for (int k2 = 2; k2 <= 256; k2 <<= 1) {
        for (int j = k2 >> 1; j >= 1; j >>= 1) {
            int i = tid, ixj = i ^ j;
            if (ixj > i) {
                bool up = ((i & k2) == 0);
                unsigned a = eqbuf[i], b = eqbuf[ixj];
                if ((a > b) == up) { eqbuf[i] = b; eqbuf[ixj] = a; }
            }
            __syncthreads();
        }
    }
    int cg = cnt_gt;
    if (tid < kEq) sel[cg + tid] = eqbuf[tid];
    __syncthreads();
    for (int k2 = 2; k2 <= 128; k2 <<= 1) {
        for (int j = k2 >> 1; j >= 1; j >>= 1) {
            if (tid < 128) {
                int i = tid, ixj = i ^ j;
                if (ixj > i) {
                    bool up = ((i & k2) == 0);
                    unsigned a = sel[i], b = sel[ixj];
                    if ((a > b) == up) { sel[i] = b; sel[ixj] = a; }
                }
            }
            __syncthreads();
        }
    }
    if (tid < WSZc) indices[(size_t)bhc*WSZc + tid] = (int)sel[tid];
}

// ---------------------------------------------------------------------------
// Kernel 2b: invert the gather map. For each entry e=(bh,c,i): tok=indices[e];
// record (c*128+i) into slots[(bh,tok)]. Exact counts; overflow -> list.
// ---------------------------------------------------------------------------
__global__ __launch_bounds__(256) void k_invert(const int* __restrict__ indices,
                                                unsigned* __restrict__ cnt,
                                                unsigned short* __restrict__ slots,
                                                unsigned* __restrict__ ovf) {
    int e = blockIdx.x*256 + threadIdx.x;          // [0, BH*NC*WSZ)
    int bh = e >> 13;                              // / (NC*WSZ)
    int rem = e & 8191;                            // c*128+i
    int tok = indices[e];
    unsigned row = ((unsigned)bh << 13) + (unsigned)tok;
    unsigned pos = atomicAdd(&cnt[row], 1u);
    if (pos < MAXPc) slots[(size_t)row*MAXPc + pos] = (unsigned short)rem;
    else {
        unsigned o = atomicAdd(&ovf[0], 1u);
        if (o < OVFCAP) ovf[1+o] = (unsigned)e;
    }
}

// ---------------------------------------------------------------------------
// Kernel 3: per (bh,c) fused attention, fp16 LDS staging, in-register softmax.
// Writes bo[bhc][i][d] fp32 coalesced (no atomics).
// shift(rel)[i][j] = rel[i][127+j-i] for j<=i else 0.
// ---------------------------------------------------------------------------
__global__ __launch_bounds__(256, 2) void k_attn(const float* __restrict__ qk,
                                                 const float* __restrict__ v,
                                                 const float* __restrict__ relw,
                                                 const int* __restrict__ indices,
                                                 float* __restrict__ bo) {
    __shared__ __align__(16) h16 qh[Dc][136];     // q^T [d][i]
    __shared__ __align__(16) h16 wv[9216];        // rel_w^T [d][m] s136 / later v [j][d] s72
    __shared__ __align__(16) h16 pt[WSZc][132];   // rel then P, transposed [j][i]
    __shared__ int   sidx[WSZc];
    __shared__ float sinv[WSZc];

    int tid = threadIdx.x;
    int bhc = blockIdx.x;
    int bh  = bhc >> 6;
    int h   = bh & (Hc-1);

    for (int i2 = tid; i2 < (WSZc*132)/2; i2 += 256) ((unsigned*)pt)[i2] = 0u;
    if (tid < WSZc) sidx[tid] = indices[(size_t)bhc*WSZc + tid];
    __syncthreads();

    {   // stage q rows (gathered) and rel_weights rows, fp32->fp16, transposed
        int i = tid >> 1, hf = tid & 1;
        const float* qrow = qk   + ((size_t)bh*Tc + sidx[i])*Dc + hf*32;
        const float* wrow = relw + ((size_t)i*Hc + h)*Dc + hf*32;
        #pragma unroll
        for (int k = 0; k < 32; k += 4) {
            float4 fq = *(const float4*)(qrow + k);
            float4 fw = *(const float4*)(wrow + k);
            int d = hf*32 + k;
            qh[d+0][i] = (h16)fq.x; qh[d+1][i] = (h16)fq.y;
            qh[d+2][i] = (h16)fq.z; qh[d+3][i] = (h16)fq.w;
            wv[(d+0)*136 + i] = (h16)fw.x; wv[(d+1)*136 + i] = (h16)fw.y;
            wv[(d+2)*136 + i] = (h16)fw.z; wv[(d+3)*136 + i] = (h16)fw.w;
        }
    }
    __syncthreads();

    if (tid < WSZc) {   // sinv[j] = scale / max(||k_j||, 1e-12)
        float n2 = 0.f;
        #pragma unroll 8
        for (int d = 0; d < Dc; d++) { float xq = (float)qh[d][tid]; n2 += xq*xq; }
        float nr = sqrtf(n2);
        if (nr < 1e-12f) nr = 1e-12f;
        sinv[tid] = 0.125f / nr;
    }
    __syncthreads();

    int ty = tid >> 4, tx = tid & 15;
    int i0 = ty*8, j0 = tx*8;

    {   // A1: rel[i][m] = q_i . rw_m ; scatter scaled into pt[m-127+i][i]
        float acc[8][8];
        #pragma unroll
        for (int a = 0; a < 8; a++)
            #pragma unroll
            for (int b = 0; b < 8; b++) acc[a][b] = 0.0f;
        #pragma unroll 4
        for (int d = 0; d < Dc; d++) {
            half8 hq = *(const half8*)&qh[d][i0];
            half8 hw = *(const half8*)&wv[d*136 + j0];
            float qv[8], wvv[8];
            #pragma unroll
            for (int k2 = 0; k2 < 8; k2++) { qv[k2] = (float)hq[k2]; wvv[k2] = (float)hw[k2]; }
            #pragma unroll
            for (int a = 0; a < 8; a++)
                #pragma unroll
                for (int b = 0; b < 8; b++) acc[a][b] += qv[a]*wvv[b];
        }
        #pragma unroll
        for (int a = 0; a < 8; a++) {
            #pragma unroll
            for (int b = 0; b < 8; b++) {
                int i = i0 + a, m = j0 + b;
                int j = m - (WSZc-1) + i;
                if (j >= 0) pt[j][i] = (h16)(acc[a][b]*0.125f);
            }
        }
    }
    __syncthreads();

    // prefetch v rows (gathered) into registers; overlaps A2 compute
    float4 vreg[8];
    {
        int vj = tid >> 1, vh = tid & 1;
        const float* vrow = v + ((size_t)bh*Tc + sidx[vj])*Dc + vh*32;
        #pragma unroll
        for (int r = 0; r < 8; r++) vreg[r] = *(const float4*)(vrow + r*4);
    }

    float acc[8][8];
    {   // A2: S = (q.q^T)*sinv + rel, diag mask  (S stays in registers)
        #pragma unroll
        for (int a = 0; a < 8; a++)
            #pragma unroll
            for (int b = 0; b < 8; b++) acc[a][b] = 0.0f;
        #pragma unroll 4
        for (int d = 0; d < Dc; d++) {
            half8 hq = *(const half8*)&qh[d][i0];
            half8 hk = *(const half8*)&qh[d][j0];
            float qv[8], kv[8];
            #pragma unroll
            for (int k2 = 0; k2 < 8; k2++) { qv[k2] = (float)hq[k2]; kv[k2] = (float)hk[k2]; }
            #pragma unroll
            for (int a = 0; a < 8; a++)
                #pragma unroll
                for (int b = 0; b < 8; b++) acc[a][b] += qv[a]*kv[b];
        }
        #pragma unroll
        for (int b = 0; b < 8; b++) {
            int j = j0 + b;
            float sj = sinv[j];
            #pragma unroll
            for (int a = 0; a < 8; a++) {
                int i = i0 + a;
                float rel = (float)pt[j][i];
                float s = acc[a][b]*sj + rel;
                if (i == j) s = -50000.0f;
                acc[a][b] = s;
            }
        }
    }
    __syncthreads();   // all rel reads from pt done; pt reusable for P

    {   // store v regs -> LDS (wv space, rel_w dead), fp16 rows [j][d] s72
        int vj = tid >> 1, vh = tid & 1;
        h16* vb = &wv[vj*72 + vh*32];
        #pragma unroll
        for (int r = 0; r < 4; r++) {
            half8 hv;
            float4 f0 = vreg[2*r], f1 = vreg[2*r+1];
            hv[0]=(h16)f0.x; hv[1]=(h16)f0.y; hv[2]=(h16)f0.z; hv[3]=(h16)f0.w;
            hv[4]=(h16)f1.x; hv[5]=(h16)f1.y; hv[6]=(h16)f1.z; hv[7]=(h16)f1.w;
            *(half8*)(vb + r*8) = hv;
        }
    }

    {   // in-register softmax across the 16-lane tx-group (rows i0..i0+7)
        float rmax[8], rsum[8];
        #pragma unroll
        for (int a = 0; a < 8; a++) {
            float m = acc[a][0];
            #pragma unroll
            for (int b = 1; b < 8; b++) m = fmaxf(m, acc[a][b]);
            #pragma unroll
            for (int st = 1; st <= 8; st <<= 1) m = fmaxf(m, __shfl_xor(m, st, 64));
            rmax[a] = m;
        }
        #pragma unroll
        for (int a = 0; a < 8; a++) {
            float s = 0.f;
            #pragma unroll
            for (int b = 0; b < 8; b++) {
                float e = __expf(acc[a][b] - rmax[a]);
                acc[a][b] = e; s += e;
            }
            #pragma unroll
            for (int st = 1; st <= 8; st <<= 1) s += __shfl_xor(s, st, 64);
            rsum[a] = 1.0f / s;
        }
        #pragma unroll
        for (int b = 0; b < 8; b++) {
            half4 p0, p1;
            #pragma unroll
            for (int a = 0; a < 4; a++) p0[a] = (h16)(acc[a][b]*rsum[a]);
            #pragma unroll
            for (int a = 0; a < 4; a++) p1[a] = (h16)(acc[a+4][b]*rsum[a+4]);
            *(half4*)&pt[j0+b][i0]   = p0;
            *(half4*)&pt[j0+b][i0+4] = p1;
        }
    }
    __syncthreads();

    {   // C: bo[i][d] = sum_j P[i][j]*v[j][d] ; coalesced store to bo
        int tyc = tid >> 3, txc = tid & 7;
        int ii0 = tyc*4, d0 = txc*8;
        float acc2[4][8];
        #pragma unroll
        for (int a = 0; a < 4; a++)
            #pragma unroll
            for (int b = 0; b < 8; b++) acc2[a][b] = 0.0f;
        #pragma unroll 2
        for (int j = 0; j < WSZc; j++) {
            half4 hp = *(const half4*)&pt[j][ii0];
            half8 hv = *(const half8*)&wv[j*72 + d0];
            float pv[4], vvv[8];
            #pragma unroll
            for (int k2 = 0; k2 < 4; k2++) pv[k2] = (float)hp[k2];
            #pragma unroll
            for (int k2 = 0; k2 < 8; k2++) vvv[k2] = (float)hv[k2];
            #pragma unroll
            for (int a = 0; a < 4; a++)
                #pragma unroll
                for (int b = 0; b < 8; b++) acc2[a][b] += pv[a]*vvv[b];
        }
        #pragma unroll
        for (int a = 0; a < 4; a++) {
            float* op = bo + ((size_t)bhc*WSZc + ii0 + a)*Dc + d0;
            float4 s0 = {acc2[a][0], acc2[a][1], acc2[a][2], acc2[a][3]};
            float4 s1 = {acc2[a][4], acc2[a][5], acc2[a][6], acc2[a][7]};
            *(float4*)(op)     = s0;
            *(float4*)(op + 4) = s1;
        }
    }
}

// ---------------------------------------------------------------------------
// Kernel 3b: rare-overflow path — add contributions beyond MAXPc into out.
// ---------------------------------------------------------------------------
__global__ __launch_bounds__(256) void k_ovf(const unsigned* __restrict__ ovf,
                                             const int* __restrict__ indices,
                                             const float* __restrict__ bo,
                                             float* __restrict__ out) {
    unsigned n = ovf[0]; if (n > OVFCAP) n = OVFCAP;
    int lane = threadIdx.x & 63, w = threadIdx.x >> 6;
    for (unsigned i = w; i < n; i += 4) {
        unsigned e = ovf[1+i];
        int bh = (int)(e >> 13); int rem = (int)(e & 8191); int tok = indices[e];
        atomicAdd(&out[(((size_t)bh << 13) + tok)*Dc + lane],
                  bo[(((size_t)bh << 13) + rem)*Dc + lane]);
    }
}

// ---------------------------------------------------------------------------
// Kernel 4: gather-sum: out[bh,t,d] = (extras + sum_p bo[bh, slot_p, d])
//                                     / (cnt + 1e-5).  One wave per row.
// ---------------------------------------------------------------------------
__global__ __launch_bounds__(256) void k_final(const float* __restrict__ bo,
                                               const unsigned short* __restrict__ slots,
                                               const unsigned* __restrict__ cnt,
                                               float* __restrict__ out) {
    int row  = blockIdx.x*4 + (threadIdx.x >> 6);   // [0, BH*T)
    int lane = threadIdx.x & 63;
    unsigned c = cnt[row];
    unsigned m = c < MAXPc ? c : MAXPc;
    int bh = row >> 13;
    float acc = out[(size_t)row*Dc + lane];          // overflow extras (usually 0)
    const unsigned short* sl = slots + (size_t)row*MAXPc;
    for (unsigned p = 0; p < m; p++) {
        unsigned rem = sl[p];
        acc += bo[(((size_t)bh << 13) + rem)*Dc + lane];
    }
    out[(size_t)row*Dc + lane] = acc * (1.0f/((float)c + 1e-5f));
    if (blockIdx.x == 0 && threadIdx.x == 0)
        out[OUT_ELEMS] = out[OUT_ELEMS] * (float)(1e-4 / 16777216.0);
}

extern "C" void kernel_launch(void* const* d_in, const int* in_sizes, int n_in,
                              void* d_out, int out_size, void* d_ws, size_t ws_size,
                              hipStream_t stream) {
    const float* qk    = (const float*)d_in[0];
    const float* v     = (const float*)d_in[1];
    const float* means = (const float*)d_in[2];
    const float* relw  = (const float*)d_in[3];
    float* out = (float*)d_out;
    char*  ws  = (char*)d_ws;

    // workspace layout (bo aliases dists: dists dead after k_topk)
    size_t off = 0;
    float* dists = (float*)(ws + off);                      // 64 MB
    float* bo    = dists;
    off += (size_t)BHc*NCc*Tc*4;
    int* indices = (int*)(ws + off); off += (size_t)BHc*NCc*WSZc*4;        // 1 MB
    unsigned* cnt = (unsigned*)(ws + off); off += (size_t)BHc*Tc*4;        // 1 MB
    unsigned short* slots = (unsigned short*)(ws + off);
    off += (size_t)BHc*Tc*MAXPc*2;                                          // 8 MB
    unsigned* ovf = (unsigned*)(ws + off);                                  // 16 KB

    hipMemsetAsync(d_out, 0, (size_t)out_size*sizeof(float), stream);
    hipMemsetAsync(cnt, 0, (size_t)BHc*Tc*4, stream);
    hipMemsetAsync(ovf, 0, 4, stream);

    k_dists <<<BHc*(Tc/256), 256, 0, stream>>>(qk, means, dists, out + OUT_ELEMS);
    k_topk  <<<BHc*NCc,      256, 0, stream>>>(dists, indices);
    k_invert<<<BHc*NCc*WSZc/256, 256, 0, stream>>>(indices, cnt, slots, ovf);
    k_attn  <<<BHc*NCc,      256, 0, stream>>>(qk, v, relw, indices, bo);
    k_ovf   <<<1,            256, 0, stream>>>(ovf, indices, bo, out);
    k_final <<<BHc*Tc/4,     256, 0, stream>>>(bo, slots, cnt, out);
}

// Round 4
// 490.604 us; speedup vs baseline: 2.2847x; 1.2898x over previous
//
#include <hip/hip_runtime.h>
#include <math.h>

typedef _Float16 h16;
typedef _Float16 f16x8 __attribute__((ext_vector_type(8)));
typedef float f32x4 __attribute__((ext_vector_type(4)));

#define Bc 4
#define Hc 8
#define Tc 8192
#define Dc 64
#define NCc 64
#define WSZc 128
#define BHc (Bc*Hc)
#define MAXPc 16
#define OVFCAP 4095
#define OUT_ELEMS (16777216u)   // B*H*T*D

#define MFMA16(a,b,c) __builtin_amdgcn_mfma_f32_16x16x32_f16(a,b,c,0,0,0)

// ---------------------------------------------------------------------------
// Kernel 1: dists[bh][c][t] = dot(l2norm(qk[bh][t]), means[h][c])  (fp32)
// plus commitment-loss raw sum atomically added into loss slot aux[1].
// ---------------------------------------------------------------------------
__global__ __launch_bounds__(256) void k_dists(const float* __restrict__ qk,
                                               const float* __restrict__ means,
                                               float* __restrict__ dists,
                                               float* __restrict__ loss_acc) {
    __shared__ float sm[NCc*Dc];       // means[h], 16 KB
    __shared__ float red[4];
    int tid = threadIdx.x;
    int blk = blockIdx.x;              // [0, BH*32)
    int bh  = blk >> 5;                // T/256 = 32 chunks per bh
    int chunk = blk & 31;
    int h = bh & (Hc-1);

    const float* mh = means + (size_t)h*NCc*Dc;
    for (int i = tid; i < NCc*Dc; i += 256) sm[i] = mh[i];
    __syncthreads();

    int t = chunk*256 + tid;
    const float* qrow = qk + ((size_t)bh*Tc + t)*Dc;
    float q[Dc];
    #pragma unroll
    for (int d = 0; d < Dc; d += 4) {
        float4 f = *(const float4*)(qrow + d);
        q[d] = f.x; q[d+1] = f.y; q[d+2] = f.z; q[d+3] = f.w;
    }
    float n2 = 0.f;
    #pragma unroll
    for (int d = 0; d < Dc; d++) n2 += q[d]*q[d];
    float nrm = sqrtf(n2);
    if (nrm < 1e-12f) nrm = 1e-12f;
    float inv = 1.0f/nrm;

    float best = -3.4e38f; int bc = 0;
    float* dbase = dists + ((size_t)bh*NCc)*Tc + (size_t)chunk*256 + tid;
    for (int c = 0; c < NCc; c++) {
        float acc = 0.f;
        const float* mc = sm + c*Dc;
        #pragma unroll
        for (int d = 0; d < Dc; d++) acc += q[d]*mc[d];
        float dv = acc*inv;
        dbase[(size_t)c*Tc] = dv;
        if (dv > best) { best = dv; bc = c; }   // strict > : first max wins
    }
    float ls = 0.f;
    const float* mb = sm + bc*Dc;
    #pragma unroll
    for (int d = 0; d < Dc; d++) {
        float diff = q[d]*inv - mb[d];
        ls += diff*diff;
    }
    float lf = ls;
    #pragma unroll
    for (int o = 32; o >= 1; o >>= 1) lf += __shfl_down(lf, o, 64);
    if ((tid & 63) == 0) red[tid >> 6] = lf;
    __syncthreads();
    if (tid == 0) atomicAdd(loss_acc, red[0]+red[1]+red[2]+red[3]);
}

// ---------------------------------------------------------------------------
// Kernel 2: per (bh,c) exact top-128 of 8192 (ties: lower index), sorted asc.
// Per-wave histograms kill the same-bucket LDS-atomic serialization.
// ---------------------------------------------------------------------------
__global__ __launch_bounds__(256) void k_topk(const float* __restrict__ dists,
                                              int* __restrict__ indices) {
    __shared__ unsigned keys[Tc];      // 32 KB
    __shared__ unsigned hist[4][256];  // 4 KB (per-wave)
    __shared__ unsigned sh_prefix;
    __shared__ int      sh_k;
    __shared__ int      cnt_gt, cnt_eq;
    __shared__ unsigned eqbuf[256];
    __shared__ unsigned sel[WSZc];

    int tid = threadIdx.x;
    int wid = tid >> 6;
    int bhc = blockIdx.x;
    const float* dp = dists + (size_t)bhc*Tc;

    for (int t = tid; t < Tc; t += 256) {
        unsigned u = __float_as_uint(dp[t]);
        u = (u & 0x80000000u) ? ~u : (u | 0x80000000u);  // order-preserving map
        keys[t] = u;
    }
    if (tid == 0) { sh_k = WSZc; sh_prefix = 0u; cnt_gt = 0; cnt_eq = 0; }
    __syncthreads();

    for (int pass = 0; pass < 4; pass++) {
        int shift = 24 - 8*pass;
        for (int i = tid; i < 1024; i += 256) ((unsigned*)hist)[i] = 0u;
        __syncthreads();
        unsigned pref = sh_prefix;
        unsigned long long hm = ~((1ull << (shift+8)) - 1ull);
        for (int t = tid; t < Tc; t += 256) {
            unsigned ky = keys[t];
            if ((((unsigned long long)ky) & hm) == (((unsigned long long)pref) & hm))
                atomicAdd(&hist[wid][(ky >> shift) & 255u], 1u);
        }
        __syncthreads();
        hist[0][tid] += hist[1][tid] + hist[2][tid] + hist[3][tid];
        __syncthreads();
        if (tid == 0) {
            int k = sh_k; unsigned cum = 0;
            for (int b = 255; b >= 0; b--) {
                unsigned hb = hist[0][b];
                if (cum + hb >= (unsigned)k) {
                    sh_k = k - (int)cum;
                    sh_prefix = pref | ((unsigned)b << shift);
                    break;
                }
                cum += hb;
            }
        }
        __syncthreads();
    }
    unsigned Kthr = sh_prefix;
    int kEq = sh_k;

    for (int t = tid; t < Tc; t += 256) {
        unsigned ky = keys[t];
        if (ky > Kthr) {
            int p = atomicAdd(&cnt_gt, 1);
            sel[p] = (unsigned)t;
        } else if (ky == Kthr) {
            int p = atomicAdd(&cnt_eq, 1);
            if (p < 256) eqbuf[p] = (unsigned)t;
        }
    }
    __syncthreads();
    int ce = cnt_eq; if (ce > 256) ce = 256;
    if (tid >= ce) eqbuf[tid] = 0xFFFFFFFFu;
    __syncthreads();
    for (int k2 = 2; k2 <= 256; k2 <<= 1) {
        for (int j = k2 >> 1; j >= 1; j >>= 1) {
            int i = tid, ixj = i ^ j;
            if (ixj > i) {
                bool up = ((i & k2) == 0);
                unsigned a = eqbuf[i], b = eqbuf[ixj];
                if ((a > b) == up) { eqbuf[i] = b; eqbuf[ixj] = a; }
            }
            __syncthreads();
        }
    }
    int cg = cnt_gt;
    if (tid < kEq) sel[cg + tid] = eqbuf[tid];
    __syncthreads();
    for (int k2 = 2; k2 <= 128; k2 <<= 1) {
        for (int j = k2 >> 1; j >= 1; j >>= 1) {
            if (tid < 128) {
                int i = tid, ixj = i ^ j;
                if (ixj > i) {
                    bool up = ((i & k2) == 0);
                    unsigned a = sel[i], b = sel[ixj];
                    if ((a > b) == up) { sel[i] = b; sel[ixj] = a; }
                }
            }
            __syncthreads();
        }
    }
    if (tid < WSZc) indices[(size_t)bhc*WSZc + tid] = (int)sel[tid];
}

// ---------------------------------------------------------------------------
// Kernel 2b: invert the gather map. aux[0]=ovf count, aux[2..]=ovf entries.
// ---------------------------------------------------------------------------
__global__ __launch_bounds__(256) void k_invert(const int* __restrict__ indices,
                                                unsigned* __restrict__ cnt,
                                                unsigned short* __restrict__ slots,
                                                unsigned* __restrict__ aux) {
    int e = blockIdx.x*256 + threadIdx.x;          // [0, BH*NC*WSZ)
    int bh = e >> 13;
    int rem = e & 8191;                            // c*128+i
    int tok = indices[e];
    unsigned row = ((unsigned)bh << 13) + (unsigned)tok;
    unsigned pos = atomicAdd(&cnt[row], 1u);
    if (pos < MAXPc) slots[(size_t)row*MAXPc + pos] = (unsigned short)rem;
    else {
        unsigned o = atomicAdd(&aux[0], 1u);
        if (o < OVFCAP) aux[2+o] = (unsigned)e;
    }
}

// ---------------------------------------------------------------------------
// Kernel 3: per (bh,c) fused attention via f16 MFMA (16x16x32).
// Wave w owns rows [32w, 32w+32). shift(rel)[i][j] = rel[i][127+j-i], j<=i.
// LDS: qf (q rows f16 s72), uv (rel_w rows s72, then v^T s136), pt (rel/P, s136).
// ---------------------------------------------------------------------------
__global__ __launch_bounds__(256, 2) void k_attn(const float* __restrict__ qk,
                                                 const float* __restrict__ v,
                                                 const float* __restrict__ relw,
                                                 const int* __restrict__ indices,
                                                 float* __restrict__ bo) {
    __shared__ __align__(16) h16 qf[128*72];      // 18432 B
    __shared__ __align__(16) h16 uv[128*72];      // 18432 B (wf then vt[64][136])
    __shared__ __align__(16) h16 pt[128*136];     // 34816 B
    __shared__ int   sidx[128];
    __shared__ float sinv[128];

    int tid = threadIdx.x;
    int bhc = blockIdx.x, bh = bhc >> 6, h = bh & (Hc-1);
    int lane = tid & 63, wid = tid >> 6;
    int quad = lane >> 4, lj = lane & 15;
    int i0 = wid*32;

    for (int i = tid; i < 128*136/2; i += 256) ((unsigned*)pt)[i] = 0u;
    if (tid < 128) sidx[tid] = indices[(size_t)bhc*WSZc + tid];
    __syncthreads();

    {   // stage q (gathered) + rel_w rows fp32->f16; sinv on the fly
        int i = tid >> 1, hf = tid & 1;
        const float* qrow = qk   + ((size_t)bh*Tc + sidx[i])*Dc + hf*32;
        const float* wrow = relw + ((size_t)i*Hc + h)*Dc + hf*32;
        float n2 = 0.f;
        #pragma unroll
        for (int k8 = 0; k8 < 4; k8++) {
            float4 a = *(const float4*)(qrow + k8*8);
            float4 b = *(const float4*)(qrow + k8*8 + 4);
            float4 c = *(const float4*)(wrow + k8*8);
            float4 d = *(const float4*)(wrow + k8*8 + 4);
            n2 += a.x*a.x + a.y*a.y + a.z*a.z + a.w*a.w
                + b.x*b.x + b.y*b.y + b.z*b.z + b.w*b.w;
            f16x8 hq = {(h16)a.x,(h16)a.y,(h16)a.z,(h16)a.w,
                        (h16)b.x,(h16)b.y,(h16)b.z,(h16)b.w};
            f16x8 hw = {(h16)c.x,(h16)c.y,(h16)c.z,(h16)c.w,
                        (h16)d.x,(h16)d.y,(h16)d.z,(h16)d.w};
            *(f16x8*)&qf[i*72 + hf*32 + k8*8] = hq;
            *(f16x8*)&uv[i*72 + hf*32 + k8*8] = hw;
        }
        n2 += __shfl_xor(n2, 1, 64);
        if (hf == 0) {
            float nr = sqrtf(n2); if (nr < 1e-12f) nr = 1e-12f;
            sinv[i] = 0.125f / nr;
        }
    }
    __syncthreads();

    {   // A1: REL[i][m] = q_i . w_m (K=64); scatter *0.125 into pt[i][m-127+i]
        f32x4 accR[2][8];
        #pragma unroll
        for (int mt = 0; mt < 2; mt++)
            #pragma unroll
            for (int nt = 0; nt < 8; nt++)
                #pragma unroll
                for (int e = 0; e < 4; e++) accR[mt][nt][e] = 0.f;
        #pragma unroll
        for (int k0 = 0; k0 < 64; k0 += 32) {
            f16x8 a0 = *(const f16x8*)&qf[(i0 + lj)*72 + k0 + quad*8];
            f16x8 a1 = *(const f16x8*)&qf[(i0 + 16 + lj)*72 + k0 + quad*8];
            #pragma unroll
            for (int nt = 0; nt < 8; nt++) {
                f16x8 bf = *(const f16x8*)&uv[(nt*16 + lj)*72 + k0 + quad*8];
                accR[0][nt] = MFMA16(a0, bf, accR[0][nt]);
                accR[1][nt] = MFMA16(a1, bf, accR[1][nt]);
            }
        }
        #pragma unroll
        for (int mt = 0; mt < 2; mt++)
            #pragma unroll
            for (int nt = 0; nt < 8; nt++)
                #pragma unroll
                for (int r = 0; r < 4; r++) {
                    int i = i0 + mt*16 + quad*4 + r;
                    int j = nt*16 + lj - 127 + i;
                    if (j >= 0) pt[i*136 + j] = (h16)(accR[mt][nt][r] * 0.125f);
                }
    }

    // prefetch v rows (gathered) into registers
    float4 vr[8];
    {
        int j = tid >> 1, hf = tid & 1;
        const float* vrow = v + ((size_t)bh*Tc + sidx[j])*Dc + hf*32;
        #pragma unroll
        for (int r = 0; r < 8; r++) vr[r] = *(const float4*)(vrow + r*4);
    }
    __syncthreads();   // all waves done reading uv(rel_w) -> region reusable

    f32x4 accS[2][8];
    #pragma unroll
    for (int mt = 0; mt < 2; mt++)
        #pragma unroll
        for (int nt = 0; nt < 8; nt++)
            #pragma unroll
            for (int e = 0; e < 4; e++) accS[mt][nt][e] = 0.f;
    #pragma unroll
    for (int k0 = 0; k0 < 64; k0 += 32) {   // A2: S = Q.Q^T
        f16x8 a0 = *(const f16x8*)&qf[(i0 + lj)*72 + k0 + quad*8];
        f16x8 a1 = *(const f16x8*)&qf[(i0 + 16 + lj)*72 + k0 + quad*8];
        #pragma unroll
        for (int nt = 0; nt < 8; nt++) {
            f16x8 bf = *(const f16x8*)&qf[(nt*16 + lj)*72 + k0 + quad*8];
            accS[0][nt] = MFMA16(a0, bf, accS[0][nt]);
            accS[1][nt] = MFMA16(a1, bf, accS[1][nt]);
        }
    }
    #pragma unroll
    for (int nt = 0; nt < 8; nt++) {   // scale + rel + diag mask
        int j = nt*16 + lj;
        float sj = sinv[j];
        #pragma unroll
        for (int mt = 0; mt < 2; mt++)
            #pragma unroll
            for (int r = 0; r < 4; r++) {
                int i = i0 + mt*16 + quad*4 + r;
                float s = accS[mt][nt][r]*sj + (float)pt[i*136 + j];
                accS[mt][nt][r] = (i == j) ? -50000.0f : s;
            }
    }
    #pragma unroll
    for (int mt = 0; mt < 2; mt++)      // softmax (rows live in 16-lane quads)
        #pragma unroll
        for (int r = 0; r < 4; r++) {
            float mx = accS[mt][0][r];
            #pragma unroll
            for (int nt = 1; nt < 8; nt++) mx = fmaxf(mx, accS[mt][nt][r]);
            #pragma unroll
            for (int st = 1; st <= 8; st <<= 1) mx = fmaxf(mx, __shfl_xor(mx, st, 64));
            float sum = 0.f;
            #pragma unroll
            for (int nt = 0; nt < 8; nt++) {
                float e = __expf(accS[mt][nt][r] - mx);
                accS[mt][nt][r] = e; sum += e;
            }
            #pragma unroll
            for (int st = 1; st <= 8; st <<= 1) sum += __shfl_xor(sum, st, 64);
            float inv = 1.0f/sum;
            #pragma unroll
            for (int nt = 0; nt < 8; nt++) accS[mt][nt][r] *= inv;
        }
    #pragma unroll
    for (int mt = 0; mt < 2; mt++)      // write P (f16) to pt (own rows)
        #pragma unroll
        for (int nt = 0; nt < 8; nt++)
            #pragma unroll
            for (int r = 0; r < 4; r++) {
                int i = i0 + mt*16 + quad*4 + r;
                pt[i*136 + nt*16 + lj] = (h16)accS[mt][nt][r];
            }
    {   // store v^T into uv: vt[d][j], stride 136
        int j = tid >> 1, hf = tid & 1;
        #pragma unroll
        for (int r = 0; r < 8; r++) {
            int d0 = hf*32 + r*4;
            float4 f = vr[r];
            uv[(d0+0)*136 + j] = (h16)f.x;
            uv[(d0+1)*136 + j] = (h16)f.y;
            uv[(d0+2)*136 + j] = (h16)f.z;
            uv[(d0+3)*136 + j] = (h16)f.w;
        }
    }
    __syncthreads();

    f32x4 accO[2][4];
    #pragma unroll
    for (int mt = 0; mt < 2; mt++)
        #pragma unroll
        for (int nt = 0; nt < 4; nt++)
            #pragma unroll
            for (int e = 0; e < 4; e++) accO[mt][nt][e] = 0.f;
    #pragma unroll
    for (int k0 = 0; k0 < 128; k0 += 32) {   // O = P.V (K=128)
        f16x8 a0 = *(const f16x8*)&pt[(i0 + lj)*136 + k0 + quad*8];
        f16x8 a1 = *(const f16x8*)&pt[(i0 + 16 + lj)*136 + k0 + quad*8];
        #pragma unroll
        for (int nt = 0; nt < 4; nt++) {
            f16x8 bf = *(const f16x8*)&uv[(nt*16 + lj)*136 + k0 + quad*8];
            accO[0][nt] = MFMA16(a0, bf, accO[0][nt]);
            accO[1][nt] = MFMA16(a1, bf, accO[1][nt]);
        }
    }
    #pragma unroll
    for (int mt = 0; mt < 2; mt++)
        #pragma unroll
        for (int nt = 0; nt < 4; nt++)
            #pragma unroll
            for (int r = 0; r < 4; r++) {
                int i = i0 + mt*16 + quad*4 + r;
                bo[((size_t)bhc*WSZc + i)*Dc + nt*16 + lj] = accO[mt][nt][r];
            }
}

// ---------------------------------------------------------------------------
// Kernel 4: out[bh,t,:] = (sum of its bo rows + rare ovf) / (cnt+EPS); loss.
// ---------------------------------------------------------------------------
__global__ __launch_bounds__(256) void k_final(const float* __restrict__ bo,
                                               const unsigned short* __restrict__ slots,
                                               const unsigned* __restrict__ cnt,
                                               const int* __restrict__ indices,
                                               const unsigned* __restrict__ aux,
                                               float* __restrict__ out) {
    int row  = blockIdx.x*4 + (threadIdx.x >> 6);   // [0, BH*T)
    int lane = threadIdx.x & 63;
    unsigned c = cnt[row];
    unsigned m = c < MAXPc ? c : MAXPc;
    int bh = row >> 13;
    float acc = 0.f;
    const unsigned short* sl = slots + (size_t)row*MAXPc;
    for (unsigned p = 0; p < m; p++)
        acc += bo[(((size_t)bh << 13) + sl[p])*Dc + lane];
    if (c > MAXPc) {   // astronomically rare
        unsigned n = aux[0]; if (n > OVFCAP) n = OVFCAP;
        int tok = row & 8191;
        for (unsigned q = 0; q < n; q++) {
            unsigned e = aux[2+q];
            if ((int)(e >> 13) == bh && indices[e] == tok)
                acc += bo[(((size_t)bh << 13) + (e & 8191))*Dc + lane];
        }
    }
    out[(size_t)row*Dc + lane] = acc * (1.0f/((float)c + 1e-5f));
    if (row == 0 && lane == 0)
        out[OUT_ELEMS] = ((const float*)aux)[1] * (float)(1e-4 / 16777216.0);
}

extern "C" void kernel_launch(void* const* d_in, const int* in_sizes, int n_in,
                              void* d_out, int out_size, void* d_ws, size_t ws_size,
                              hipStream_t stream) {
    const float* qk    = (const float*)d_in[0];
    const float* v     = (const float*)d_in[1];
    const float* means = (const float*)d_in[2];
    const float* relw  = (const float*)d_in[3];
    float* out = (float*)d_out;
    char*  ws  = (char*)d_ws;

    // workspace layout (bo aliases dists: dists dead after k_topk)
    size_t off = 0;
    float* dists = (float*)(ws + off);
    float* bo    = dists;
    off += (size_t)BHc*NCc*Tc*4;                                           // 64 MB
    int* indices = (int*)(ws + off); off += (size_t)BHc*NCc*WSZc*4;        // 1 MB
    unsigned* cnt = (unsigned*)(ws + off); off += (size_t)BHc*Tc*4;        // 1 MB
    unsigned* aux = (unsigned*)(ws + off); off += (size_t)(2+OVFCAP)*4;    // 16 KB
    unsigned short* slots = (unsigned short*)(ws + off);
    off += (size_t)BHc*Tc*MAXPc*2;                                         // 8 MB

    // single memset covers cnt + aux (adjacent)
    hipMemsetAsync(cnt, 0, (size_t)BHc*Tc*4 + (size_t)(2+OVFCAP)*4, stream);

    k_dists <<<BHc*(Tc/256), 256, 0, stream>>>(qk, means, dists, (float*)aux + 1);
    k_topk  <<<BHc*NCc,      256, 0, stream>>>(dists, indices);
    k_invert<<<BHc*NCc*WSZc/256, 256, 0, stream>>>(indices, cnt, slots, aux);
    k_attn  <<<BHc*NCc,      256, 0, stream>>>(qk, v, relw, indices, bo);
    k_final <<<BHc*Tc/4,     256, 0, stream>>>(bo, slots, cnt, indices, aux, out);
}

// Round 5
// 392.900 us; speedup vs baseline: 2.8529x; 1.2487x over previous
//
#include <hip/hip_runtime.h>
#include <math.h>

typedef _Float16 h16;
typedef _Float16 f16x8 __attribute__((ext_vector_type(8)));
typedef float f32x4 __attribute__((ext_vector_type(4)));

#define Bc 4
#define Hc 8
#define Tc 8192
#define Dc 64
#define NCc 64
#define WSZc 128
#define BHc (Bc*Hc)
#define MAXPc 16
#define OVFCAP 4095
#define OUT_ELEMS (16777216u)   // B*H*T*D

#define MFMA16(a,b,c) __builtin_amdgcn_mfma_f32_16x16x32_f16(a,b,c,0,0,0)

// ---------------------------------------------------------------------------
// Kernel 1: dists[bh][c][t] = dot(l2norm(qk[bh][t]), means[h][c])  (fp32)
// plus commitment-loss raw sum atomically added into loss slot aux[1].
// ---------------------------------------------------------------------------
__global__ __launch_bounds__(256) void k_dists(const float* __restrict__ qk,
                                               const float* __restrict__ means,
                                               float* __restrict__ dists,
                                               float* __restrict__ loss_acc) {
    __shared__ float sm[NCc*Dc];       // means[h], 16 KB
    __shared__ float red[4];
    int tid = threadIdx.x;
    int blk = blockIdx.x;              // [0, BH*32)
    int bh  = blk >> 5;                // T/256 = 32 chunks per bh
    int chunk = blk & 31;
    int h = bh & (Hc-1);

    const float* mh = means + (size_t)h*NCc*Dc;
    for (int i = tid; i < NCc*Dc; i += 256) sm[i] = mh[i];
    __syncthreads();

    int t = chunk*256 + tid;
    const float* qrow = qk + ((size_t)bh*Tc + t)*Dc;
    float q[Dc];
    #pragma unroll
    for (int d = 0; d < Dc; d += 4) {
        float4 f = *(const float4*)(qrow + d);
        q[d] = f.x; q[d+1] = f.y; q[d+2] = f.z; q[d+3] = f.w;
    }
    float n2 = 0.f;
    #pragma unroll
    for (int d = 0; d < Dc; d++) n2 += q[d]*q[d];
    float nrm = sqrtf(n2);
    if (nrm < 1e-12f) nrm = 1e-12f;
    float inv = 1.0f/nrm;

    float best = -3.4e38f; int bc = 0;
    float* dbase = dists + ((size_t)bh*NCc)*Tc + (size_t)chunk*256 + tid;
    for (int c = 0; c < NCc; c++) {
        float acc = 0.f;
        const float* mc = sm + c*Dc;
        #pragma unroll
        for (int d = 0; d < Dc; d++) acc += q[d]*mc[d];
        float dv = acc*inv;
        dbase[(size_t)c*Tc] = dv;
        if (dv > best) { best = dv; bc = c; }   // strict > : first max wins
    }
    float ls = 0.f;
    const float* mb = sm + bc*Dc;
    #pragma unroll
    for (int d = 0; d < Dc; d++) {
        float diff = q[d]*inv - mb[d];
        ls += diff*diff;
    }
    float lf = ls;
    #pragma unroll
    for (int o = 32; o >= 1; o >>= 1) lf += __shfl_down(lf, o, 64);
    if ((tid & 63) == 0) red[tid >> 6] = lf;
    __syncthreads();
    if (tid == 0) atomicAdd(loss_acc, red[0]+red[1]+red[2]+red[3]);
}

// ---------------------------------------------------------------------------
// Kernel 2: per (bh,c) exact top-128 of 8192 (ties: lower index), sorted asc,
// with the inverse map (cnt/slots/aux) built in the same kernel.
// 12/12/8-bit radix select + bitmap popcount ranking (no bitonic common path).
// ---------------------------------------------------------------------------
__device__ inline unsigned blockScanIncl(unsigned v, volatile unsigned* wsum,
                                         int lane, int wid, unsigned* ptotal) {
    unsigned x = v;
    #pragma unroll
    for (int s = 1; s < 64; s <<= 1) {
        unsigned o = __shfl_up(x, s, 64);
        if (lane >= s) x += o;
    }
    if (lane == 63) wsum[wid] = x;
    __syncthreads();
    unsigned off = 0, tot = 0;
    #pragma unroll
    for (int w2 = 0; w2 < 4; w2++) {
        unsigned s2 = wsum[w2];
        if (w2 < wid) off += s2;
        tot += s2;
    }
    *ptotal = tot;
    return x + off;
}

__global__ __launch_bounds__(256) void k_topk(const float* __restrict__ dists,
                                              int* __restrict__ indices,
                                              unsigned* __restrict__ cnt,
                                              unsigned short* __restrict__ slots,
                                              unsigned* __restrict__ aux) {
    __shared__ unsigned keys[Tc];      // 32 KB
    __shared__ unsigned hist[4096];    // 16 KB
    __shared__ unsigned bmap[256];     // 1 KB (8192-bit selection bitmap)
    __shared__ unsigned eqbuf[256];    // 1 KB (tie candidates, rare path)
    __shared__ unsigned wsum[4];
    __shared__ unsigned sh_prefix;
    __shared__ int      sh_k, cnt_eq;

    int tid = threadIdx.x;
    int lane = tid & 63, wid = tid >> 6;
    int bhc = blockIdx.x, bh = bhc >> 6, c = bhc & 63;
    const float* dp = dists + (size_t)bhc*Tc;

    // level 0 hist zero + fused load/map/hist
    for (int i = tid; i < 4096; i += 256) hist[i] = 0u;
    if (tid == 0) { sh_k = WSZc; sh_prefix = 0u; cnt_eq = 0; }
    if (tid < 256) bmap[tid] = 0u;
    __syncthreads();
    for (int t = tid; t < Tc; t += 256) {
        unsigned u = __float_as_uint(dp[t]);
        u = (u & 0x80000000u) ? ~u : (u | 0x80000000u);  // order-preserving
        keys[t] = u;
        atomicAdd(&hist[u >> 20], 1u);
    }
    __syncthreads();

    unsigned prefix = 0u; int k = WSZc;
    #pragma unroll
    for (int lvl = 0; lvl < 3; lvl++) {
        const int shift   = (lvl == 0) ? 20 : (lvl == 1 ? 8 : 0);
        const int nper    = (lvl == 2) ? 1 : 16;           // bins per thread
        const unsigned nbm = (lvl == 2) ? 255u : 4095u;    // bin mask
        if (lvl > 0) {
            // build filtered histogram for this level
            const unsigned maskH = (lvl == 1) ? 0xFFF00000u : 0xFFFFFF00u;
            for (int i = tid; i <= (int)nbm; i += 256) hist[i] = 0u;
            __syncthreads();
            for (int t = tid; t < Tc; t += 256) {
                unsigned ky = keys[t];
                if ((ky & maskH) == prefix)
                    atomicAdd(&hist[(ky >> shift) & nbm], 1u);
            }
            __syncthreads();
        }
        // parallel crossing-bin search (suffix = total - excl_ascending)
        int tBase = tid*nper;
        unsigned psum = 0;
        for (int i = 0; i < nper; i++) psum += hist[tBase + i];
        unsigned total;
        unsigned incl = blockScanIncl(psum, wsum, lane, wid, &total);
        unsigned beyond = total - incl;          // keys in bins strictly above
        unsigned suff   = beyond + psum;
        if (beyond < (unsigned)k && (unsigned)k <= suff) {
            unsigned run = beyond;
            for (int i = nper - 1; i >= 0; i--) {
                unsigned hb = hist[tBase + i];
                run += hb;
                if (run >= (unsigned)k) {
                    sh_prefix = prefix | ((unsigned)(tBase + i) << shift);
                    sh_k = k - (int)(run - hb);
                    break;
                }
            }
        }
        __syncthreads();
        prefix = sh_prefix; k = sh_k;
        __syncthreads();
    }
    unsigned Kthr = prefix;    // exact 32-bit threshold key
    int kEq = k;               // # of threshold-equal keys to take (lowest idx)

    // collect: strict-greater -> bitmap; equal -> eqbuf
    for (int t = tid; t < Tc; t += 256) {
        unsigned ky = keys[t];
        if (ky > Kthr) atomicOr(&bmap[t >> 5], 1u << (t & 31));
        else if (ky == Kthr) {
            int p = atomicAdd(&cnt_eq, 1);
            if (p < 256) eqbuf[p] = (unsigned)t;
        }
    }
    __syncthreads();
    if (cnt_eq == kEq) {       // common path: every equal key is selected
        if (tid < kEq) {
            unsigned t = eqbuf[tid];
            atomicOr(&bmap[t >> 5], 1u << (t & 31));
        }
    } else {                   // rare: sort ties, take lowest kEq indices
        int ce = cnt_eq < 256 ? cnt_eq : 256;
        if (tid >= ce) eqbuf[tid] = 0xFFFFFFFFu;
        __syncthreads();
        for (int k2 = 2; k2 <= 256; k2 <<= 1) {
            for (int j = k2 >> 1; j >= 1; j >>= 1) {
                int i = tid, ixj = i ^ j;
                if (ixj > i) {
                    bool up = ((i & k2) == 0);
                    unsigned a = eqbuf[i], b = eqbuf[ixj];
                    if ((a > b) == up) { eqbuf[i] = b; eqbuf[ixj] = a; }
                }
                __syncthreads();
            }
        }
        if (tid < kEq) {
            unsigned t = eqbuf[tid];
            atomicOr(&bmap[t >> 5], 1u << (t & 31));
        }
    }
    __syncthreads();

    // rank via popcount prefix: indices come out sorted ascending by token
    unsigned w = bmap[tid];
    int pc = __popc(w);
    unsigned total2;
    unsigned incl2 = blockScanIncl((unsigned)pc, wsum, lane, wid, &total2);
    int pos = (int)(incl2 - pc);     // exclusive prefix = output position
    while (w) {
        int b = __ffs(w) - 1; w &= w - 1;
        int t = tid*32 + b;
        indices[(size_t)bhc*WSZc + pos] = t;
        // fused inverse map
        unsigned row = ((unsigned)bh << 13) + (unsigned)t;
        unsigned p2 = atomicAdd(&cnt[row], 1u);
        if (p2 < MAXPc) slots[(size_t)row*MAXPc + p2] = (unsigned short)(c*128 + pos);
        else {
            unsigned o = atomicAdd(&aux[0], 1u);
            if (o < OVFCAP) aux[2+o] = (unsigned)(bhc*WSZc + pos);
        }
        pos++;
    }
}

// ---------------------------------------------------------------------------
// Kernel 3: per (bh,c) fused attention via f16 MFMA (16x16x32).
// Wave w owns rows [32w, 32w+32). shift(rel)[i][j] = rel[i][127+j-i], j<=i.
// ---------------------------------------------------------------------------
__global__ __launch_bounds__(256, 2) void k_attn(const float* __restrict__ qk,
                                                 const float* __restrict__ v,
                                                 const float* __restrict__ relw,
                                                 const int* __restrict__ indices,
                                                 float* __restrict__ bo) {
    __shared__ __align__(16) h16 qf[128*72];      // 18432 B
    __shared__ __align__(16) h16 uv[128*72];      // 18432 B (wf then vt[64][136])
    __shared__ __align__(16) h16 pt[128*136];     // 34816 B
    __shared__ int   sidx[128];
    __shared__ float sinv[128];

    int tid = threadIdx.x;
    int bhc = blockIdx.x, bh = bhc >> 6, h = bh & (Hc-1);
    int lane = tid & 63, wid = tid >> 6;
    int quad = lane >> 4, lj = lane & 15;
    int i0 = wid*32;

    for (int i = tid; i < 128*136/2; i += 256) ((unsigned*)pt)[i] = 0u;
    if (tid < 128) sidx[tid] = indices[(size_t)bhc*WSZc + tid];
    __syncthreads();

    {   // stage q (gathered) + rel_w rows fp32->f16; sinv on the fly
        int i = tid >> 1, hf = tid & 1;
        const float* qrow = qk   + ((size_t)bh*Tc + sidx[i])*Dc + hf*32;
        const float* wrow = relw + ((size_t)i*Hc + h)*Dc + hf*32;
        float n2 = 0.f;
        #pragma unroll
        for (int k8 = 0; k8 < 4; k8++) {
            float4 a = *(const float4*)(qrow + k8*8);
            float4 b = *(const float4*)(qrow + k8*8 + 4);
            float4 c = *(const float4*)(wrow + k8*8);
            float4 d = *(const float4*)(wrow + k8*8 + 4);
            n2 += a.x*a.x + a.y*a.y + a.z*a.z + a.w*a.w
                + b.x*b.x + b.y*b.y + b.z*b.z + b.w*b.w;
            f16x8 hq = {(h16)a.x,(h16)a.y,(h16)a.z,(h16)a.w,
                        (h16)b.x,(h16)b.y,(h16)b.z,(h16)b.w};
            f16x8 hw = {(h16)c.x,(h16)c.y,(h16)c.z,(h16)c.w,
                        (h16)d.x,(h16)d.y,(h16)d.z,(h16)d.w};
            *(f16x8*)&qf[i*72 + hf*32 + k8*8] = hq;
            *(f16x8*)&uv[i*72 + hf*32 + k8*8] = hw;
        }
        n2 += __shfl_xor(n2, 1, 64);
        if (hf == 0) {
            float nr = sqrtf(n2); if (nr < 1e-12f) nr = 1e-12f;
            sinv[i] = 0.125f / nr;
        }
    }
    __syncthreads();

    {   // A1: REL[i][m] = q_i . w_m (K=64); scatter *0.125 into pt[i][m-127+i]
        f32x4 accR[2][8];
        #pragma unroll
        for (int mt = 0; mt < 2; mt++)
            #pragma unroll
            for (int nt = 0; nt < 8; nt++)
                #pragma unroll
                for (int e = 0; e < 4; e++) accR[mt][nt][e] = 0.f;
        #pragma unroll
        for (int k0 = 0; k0 < 64; k0 += 32) {
            f16x8 a0 = *(const f16x8*)&qf[(i0 + lj)*72 + k0 + quad*8];
            f16x8 a1 = *(const f16x8*)&qf[(i0 + 16 + lj)*72 + k0 + quad*8];
            #pragma unroll
            for (int nt = 0; nt < 8; nt++) {
                f16x8 bf = *(const f16x8*)&uv[(nt*16 + lj)*72 + k0 + quad*8];
                accR[0][nt] = MFMA16(a0, bf, accR[0][nt]);
                accR[1][nt] = MFMA16(a1, bf, accR[1][nt]);
            }
        }
        #pragma unroll
        for (int mt = 0; mt < 2; mt++)
            #pragma unroll
            for (int nt = 0; nt < 8; nt++)
                #pragma unroll
                for (int r = 0; r < 4; r++) {
                    int i = i0 + mt*16 + quad*4 + r;
                    int j = nt*16 + lj - 127 + i;
                    if (j >= 0) pt[i*136 + j] = (h16)(accR[mt][nt][r] * 0.125f);
                }
    }

    // prefetch v rows (gathered) into registers
    float4 vr[8];
    {
        int j = tid >> 1, hf = tid & 1;
        const float* vrow = v + ((size_t)bh*Tc + sidx[j])*Dc + hf*32;
        #pragma unroll
        for (int r = 0; r < 8; r++) vr[r] = *(const float4*)(vrow + r*4);
    }
    __syncthreads();   // all waves done reading uv(rel_w) -> region reusable

    f32x4 accS[2][8];
    #pragma unroll
    for (int mt = 0; mt < 2; mt++)
        #pragma unroll
        for (int nt = 0; nt < 8; nt++)
            #pragma unroll
            for (int e = 0; e < 4; e++) accS[mt][nt][e] = 0.f;
    #pragma unroll
    for (int k0 = 0; k0 < 64; k0 += 32) {   // A2: S = Q.Q^T
        f16x8 a0 = *(const f16x8*)&qf[(i0 + lj)*72 + k0 + quad*8];
        f16x8 a1 = *(const f16x8*)&qf[(i0 + 16 + lj)*72 + k0 + quad*8];
        #pragma unroll
        for (int nt = 0; nt < 8; nt++) {
            f16x8 bf = *(const f16x8*)&qf[(nt*16 + lj)*72 + k0 + quad*8];
            accS[0][nt] = MFMA16(a0, bf, accS[0][nt]);
            accS[1][nt] = MFMA16(a1, bf, accS[1][nt]);
        }
    }
    #pragma unroll
    for (int nt = 0; nt < 8; nt++) {   // scale + rel + diag mask
        int j = nt*16 + lj;
        float sj = sinv[j];
        #pragma unroll
        for (int mt = 0; mt < 2; mt++)
            #pragma unroll
            for (int r = 0; r < 4; r++) {
                int i = i0 + mt*16 + quad*4 + r;
                float s = accS[mt][nt][r]*sj + (float)pt[i*136 + j];
                accS[mt][nt][r] = (i == j) ? -50000.0f : s;
            }
    }
    #pragma unroll
    for (int mt = 0; mt < 2; mt++)      // softmax (rows live in 16-lane quads)
        #pragma unroll
        for (int r = 0; r < 4; r++) {
            float mx = accS[mt][0][r];
            #pragma unroll
            for (int nt = 1; nt < 8; nt++) mx = fmaxf(mx, accS[mt][nt][r]);
            #pragma unroll
            for (int st = 1; st <= 8; st <<= 1) mx = fmaxf(mx, __shfl_xor(mx, st, 64));
            float sum = 0.f;
            #pragma unroll
            for (int nt = 0; nt < 8; nt++) {
                float e = __expf(accS[mt][nt][r] - mx);
                accS[mt][nt][r] = e; sum += e;
            }
            #pragma unroll
            for (int st = 1; st <= 8; st <<= 1) sum += __shfl_xor(sum, st, 64);
            float inv = 1.0f/sum;
            #pragma unroll
            for (int nt = 0; nt < 8; nt++) accS[mt][nt][r] *= inv;
        }
    #pragma unroll
    for (int mt = 0; mt < 2; mt++)      // write P (f16) to pt (own rows)
        #pragma unroll
        for (int nt = 0; nt < 8; nt++)
            #pragma unroll
            for (int r = 0; r < 4; r++) {
                int i = i0 + mt*16 + quad*4 + r;
                pt[i*136 + nt*16 + lj] = (h16)accS[mt][nt][r];
            }
    {   // store v^T into uv: vt[d][j], stride 136
        int j = tid >> 1, hf = tid & 1;
        #pragma unroll
        for (int r = 0; r < 8; r++) {
            int d0 = hf*32 + r*4;
            float4 f = vr[r];
            uv[(d0+0)*136 + j] = (h16)f.x;
            uv[(d0+1)*136 + j] = (h16)f.y;
            uv[(d0+2)*136 + j] = (h16)f.z;
            uv[(d0+3)*136 + j] = (h16)f.w;
        }
    }
    __syncthreads();

    f32x4 accO[2][4];
    #pragma unroll
    for (int mt = 0; mt < 2; mt++)
        #pragma unroll
        for (int nt = 0; nt < 4; nt++)
            #pragma unroll
            for (int e = 0; e < 4; e++) accO[mt][nt][e] = 0.f;
    #pragma unroll
    for (int k0 = 0; k0 < 128; k0 += 32) {   // O = P.V (K=128)
        f16x8 a0 = *(const f16x8*)&pt[(i0 + lj)*136 + k0 + quad*8];
        f16x8 a1 = *(const f16x8*)&pt[(i0 + 16 + lj)*136 + k0 + quad*8];
        #pragma unroll
        for (int nt = 0; nt < 4; nt++) {
            f16x8 bf = *(const f16x8*)&uv[(nt*16 + lj)*136 + k0 + quad*8];
            accO[0][nt] = MFMA16(a0, bf, accO[0][nt]);
            accO[1][nt] = MFMA16(a1, bf, accO[1][nt]);
        }
    }
    #pragma unroll
    for (int mt = 0; mt < 2; mt++)
        #pragma unroll
        for (int nt = 0; nt < 4; nt++)
            #pragma unroll
            for (int r = 0; r < 4; r++) {
                int i = i0 + mt*16 + quad*4 + r;
                bo[((size_t)bhc*WSZc + i)*Dc + nt*16 + lj] = accO[mt][nt][r];
            }
}

// ---------------------------------------------------------------------------
// Kernel 4: out[bh,t,:] = (sum of its bo rows + rare ovf) / (cnt+EPS); loss.
// ---------------------------------------------------------------------------
__global__ __launch_bounds__(256) void k_final(const float* __restrict__ bo,
                                               const unsigned short* __restrict__ slots,
                                               const unsigned* __restrict__ cnt,
                                               const int* __restrict__ indices,
                                               const unsigned* __restrict__ aux,
                                               float* __restrict__ out) {
    int row  = blockIdx.x*4 + (threadIdx.x >> 6);   // [0, BH*T)
    int lane = threadIdx.x & 63;
    unsigned c = cnt[row];
    unsigned m = c < MAXPc ? c : MAXPc;
    int bh = row >> 13;
    float acc = 0.f;
    const unsigned short* sl = slots + (size_t)row*MAXPc;
    for (unsigned p = 0; p < m; p++)
        acc += bo[(((size_t)bh << 13) + sl[p])*Dc + lane];
    if (c > MAXPc) {   // astronomically rare
        unsigned n = aux[0]; if (n > OVFCAP) n = OVFCAP;
        int tok = row & 8191;
        for (unsigned q = 0; q < n; q++) {
            unsigned e = aux[2+q];
            if ((int)(e >> 13) == bh && indices[e] == tok)
                acc += bo[(((size_t)bh << 13) + (e & 8191))*Dc + lane];
        }
    }
    out[(size_t)row*Dc + lane] = acc * (1.0f/((float)c + 1e-5f));
    if (row == 0 && lane == 0)
        out[OUT_ELEMS] = ((const float*)aux)[1] * (float)(1e-4 / 16777216.0);
}

extern "C" void kernel_launch(void* const* d_in, const int* in_sizes, int n_in,
                              void* d_out, int out_size, void* d_ws, size_t ws_size,
                              hipStream_t stream) {
    const float* qk    = (const float*)d_in[0];
    const float* v     = (const float*)d_in[1];
    const float* means = (const float*)d_in[2];
    const float* relw  = (const float*)d_in[3];
    float* out = (float*)d_out;
    char*  ws  = (char*)d_ws;

    // workspace layout (bo aliases dists: dists dead after k_topk)
    size_t off = 0;
    float* dists = (float*)(ws + off);
    float* bo    = dists;
    off += (size_t)BHc*NCc*Tc*4;                                           // 64 MB
    int* indices = (int*)(ws + off); off += (size_t)BHc*NCc*WSZc*4;        // 1 MB
    unsigned* cnt = (unsigned*)(ws + off); off += (size_t)BHc*Tc*4;        // 1 MB
    unsigned* aux = (unsigned*)(ws + off); off += (size_t)(2+OVFCAP)*4;    // 16 KB
    unsigned short* slots = (unsigned short*)(ws + off);
    off += (size_t)BHc*Tc*MAXPc*2;                                         // 8 MB

    // single memset covers cnt + aux (adjacent)
    hipMemsetAsync(cnt, 0, (size_t)BHc*Tc*4 + (size_t)(2+OVFCAP)*4, stream);

    k_dists <<<BHc*(Tc/256), 256, 0, stream>>>(qk, means, dists, (float*)aux + 1);
    k_topk  <<<BHc*NCc,      256, 0, stream>>>(dists, indices, cnt, slots, aux);
    k_attn  <<<BHc*NCc,      256, 0, stream>>>(qk, v, relw, indices, bo);
    k_final <<<BHc*Tc/4,     256, 0, stream>>>(bo, slots, cnt, indices, aux, out);
}